// Round 7
// baseline (434.775 us; speedup 1.0000x reference)
//
#include <hip/hip_runtime.h>
#include <hip/hip_bf16.h>

// Problem constants (B=2, L=2048, Dm=768, di=1536, ds=16, dc=4)
#define BB 2
#define LL 2048
#define DM 768
#define DI 1536
#define DS 16
#define MM (BB*LL)   // 4096 rows
#define NCH 32       // scan chunks
#define CHL 64       // steps per chunk
#define SEQS (BB*DI*DS)  // 49152 independent scalar recurrences
#define NC2 1664     // delta GEMM fused N: 1536 (W_dt) + 32 (W_x) + 96 pad

typedef __hip_bfloat16 bf16;
typedef short bf16x8 __attribute__((ext_vector_type(8)));
typedef float f32x4  __attribute__((ext_vector_type(4)));

__device__ __forceinline__ void gl_lds16(const void* g, void* l) {
  __builtin_amdgcn_global_load_lds((const __attribute__((address_space(1))) void*)g,
                                   (__attribute__((address_space(3))) void*)l, 16, 0, 0);
}

// ---------------- fp32 -> bf16 convert (4 elems/thread) ----------------
struct bf4 { __hip_bfloat16 a, b, c, d; };
__global__ void cvt4_k(const float* __restrict__ in, __hip_bfloat16* __restrict__ out, int n4) {
  int i = blockIdx.x * 256 + threadIdx.x;
  if (i < n4) {
    float4 v = ((const float4*)in)[i];
    bf4 o = { __float2bfloat16(v.x), __float2bfloat16(v.y),
              __float2bfloat16(v.z), __float2bfloat16(v.w) };
    ((bf4*)out)[i] = o;
  }
}

// ---------------- build Wcomb[1664][1536] bf16 = [W_dt ; W_x ; 0-pad] ----------------
__global__ void wcomb_k(const float* __restrict__ Wdt, const float* __restrict__ Wx,
                        __hip_bfloat16* __restrict__ out) {
  int i = blockIdx.x * 256 + threadIdx.x;          // one float4 per thread
  if (i >= NC2 * DI / 4) return;
  int e = i * 4;
  int row = e / DI, colb = e % DI;
  float4 v;
  if (row < DI)            v = ((const float4*)Wdt)[i];
  else if (row < DI + 32)  v = *(const float4*)(Wx + (size_t)(row - DI) * DI + colb);
  else                     v = make_float4(0.f, 0.f, 0.f, 0.f);
  bf4 o = { __float2bfloat16(v.x), __float2bfloat16(v.y),
            __float2bfloat16(v.z), __float2bfloat16(v.w) };
  ((bf4*)out)[i] = o;
}

// ---------------- single-wave NT bf16 MFMA GEMM, 64x64 tile ----------------
// C[M,N] = A[M,K] * W[N,K]^T. ONE wave per block -> no barriers, no inter-wave
// convergence. 3 private LDS buffers (24 KB -> 6 blocks/CU), 2 tiles in flight,
// s_waitcnt vmcnt(8) per iter (8 gl_lds per tile). K templated -> full unroll,
// gl_lds K-offsets fold into 13-bit immediates. 16 MFMA per iter per wave.
// WAR safety (no barrier needed): per-wave in-order issue means ds_reads of a
// buffer (iter i-1, drained by lgkm waits before that iter's MFMAs) retire
// before iter i issues gl_lds writes into the same buffer.
// EPI: 0 = plain fp32 store (stride N)
//      2 = split: col<DI -> C (stride DI), else -> C2 (stride DI)   [xz GEMM]
//      3 = col<DI -> softplus(v+bias[col]) -> C (stride DI);
//          col in [DI,DI+32) -> C2 (stride 32); else discard        [delta+xdbl]
template<int EPI, int K>
__global__ __launch_bounds__(64) void gemm_w(const bf16* __restrict__ A,
                                             const bf16* __restrict__ W,
                                             float* __restrict__ C,
                                             float* __restrict__ C2,
                                             const float* __restrict__ bias,
                                             int N) {
  constexpr int ITERS = K / 32;
  __shared__ short sA[3][64 * 32];   // 4 KB per buffer
  __shared__ short sB[3][64 * 32];
  const int t = threadIdx.x;         // lane, block = 1 wave
  const int m0 = blockIdx.y * 64, n0 = blockIdx.x * 64;

  f32x4 acc[4][4] = {};

  // lane l stages row (l&15) of each 16-row block, k-chunk (l>>4)*8
  const int srow = t & 15, skoff = (t >> 4) * 8;
  const bf16* gA[4]; const bf16* gB[4];
  #pragma unroll
  for (int j = 0; j < 4; j++) {
    gA[j] = A + (size_t)(m0 + j * 16 + srow) * K + skoff;
    gB[j] = W + (size_t)(n0 + j * 16 + srow) * K + skoff;
  }

  auto issue = [&](int buf, int k0) {
    #pragma unroll
    for (int j = 0; j < 4; j++) gl_lds16(gA[j] + k0, &sA[buf][j * 512]);
    #pragma unroll
    for (int j = 0; j < 4; j++) gl_lds16(gB[j] + k0, &sB[buf][j * 512]);
  };

  issue(0, 0);
  issue(1, 32);
  #pragma unroll
  for (int it = 0; it < ITERS; it++) {
    if (it + 1 < ITERS) {
      asm volatile("s_waitcnt vmcnt(8)" ::: "memory");   // tile it complete
    } else {
      asm volatile("s_waitcnt vmcnt(0)" ::: "memory");
    }
    if (it + 2 < ITERS) issue((it + 2) % 3, (it + 2) * 32);
    const bf16x8* fA = (const bf16x8*)sA[it % 3];
    const bf16x8* fB = (const bf16x8*)sB[it % 3];
    bf16x8 af[4], bfr[4];
    #pragma unroll
    for (int i = 0; i < 4; i++) af[i]  = fA[i * 64 + t];
    #pragma unroll
    for (int j = 0; j < 4; j++) bfr[j] = fB[j * 64 + t];
    #pragma unroll
    for (int i = 0; i < 4; i++)
      #pragma unroll
      for (int j = 0; j < 4; j++)
        acc[i][j] = __builtin_amdgcn_mfma_f32_16x16x32_bf16(af[i], bfr[j], acc[i][j], 0, 0, 0);
  }

  const int q = t >> 4, mm = t & 15;
  #pragma unroll
  for (int i = 0; i < 4; i++)
    #pragma unroll
    for (int j = 0; j < 4; j++) {
      int r0  = m0 + i * 16 + q * 4;
      int col = n0 + j * 16 + mm;
      #pragma unroll
      for (int r = 0; r < 4; r++) {
        float v = acc[i][j][r];
        if (EPI == 0) {
          C[(size_t)(r0 + r) * N + col] = v;
        } else if (EPI == 2) {
          if (col < DI) C [(size_t)(r0 + r) * DI + col]        = v;
          else          C2[(size_t)(r0 + r) * DI + (col - DI)] = v;
        } else {  // EPI == 3
          if (col < DI) {
            float vv = v + bias[col];
            vv = (vv > 15.f) ? vv : __logf(1.f + __expf(vv));
            C[(size_t)(r0 + r) * DI + col] = vv;
          } else if (col < DI + 32) {
            C2[(size_t)(r0 + r) * 32 + (col - DI)] = v;
          }
        }
      }
    }
}

// ---------------- depthwise causal conv (dc=4) + SiLU; writes fp32 + bf16 ----------------
__global__ __launch_bounds__(256) void conv_silu_k(const float* __restrict__ xpart,
                                                   const float* __restrict__ Wc,
                                                   float* __restrict__ xc,
                                                   __hip_bfloat16* __restrict__ xcbf) {
  int idx = blockIdx.x * 256 + threadIdx.x;
  if (idx >= MM * DI) return;
  int d = idx % DI;
  int r = idx / DI;
  int l = r & (LL - 1);
  float4 wv = ((const float4*)Wc)[d];  // W_conv[d, 0, 0..3]
  const float* xp = xpart + (size_t)r * DI + d;
  float acc = wv.w * xp[0];
  if (l >= 1) acc += wv.z * xp[-(ptrdiff_t)DI];
  if (l >= 2) acc += wv.y * xp[-(ptrdiff_t)(2 * DI)];
  if (l >= 3) acc += wv.x * xp[-(ptrdiff_t)(3 * DI)];
  float s = acc / (1.f + __expf(-acc));   // silu
  xc[idx] = s;
  xcbf[idx] = __float2bfloat16(s);
}

// ================= chunked selective scan =================
__global__ __launch_bounds__(64) void scan_part_k(const float* __restrict__ delta,
                                                  const float* __restrict__ xdbl,
                                                  const float* __restrict__ A_log,
                                                  float* __restrict__ prodA,
                                                  float* __restrict__ hend) {
  __shared__ float sBC[CHL * 32];
  const int t = threadIdx.x;
  const int dg = blockIdx.x % (DI / 64);
  const int chunk = (blockIdx.x / (DI / 64)) % NCH;
  const int b = blockIdx.x / ((DI / 64) * NCH);
  const int d = dg * 64 + t;

  float a[16];
  #pragma unroll
  for (int s = 0; s < 16; s++) a[s] = -__expf(A_log[s]);

  const float4* src = (const float4*)(xdbl + ((size_t)b * LL + chunk * CHL) * 32);
  #pragma unroll
  for (int k = 0; k < 8; k++) ((float4*)sBC)[t + k * 64] = src[t + k * 64];
  __syncthreads();

  float h[16], p[16];
  #pragma unroll
  for (int s = 0; s < 16; s++) { h[s] = 0.f; p[s] = 1.f; }

  const float* dptr = delta + ((size_t)b * LL + chunk * CHL) * DI + d;
  #pragma unroll 2
  for (int i = 0; i < CHL; i++) {
    float dlt = dptr[(size_t)i * DI];
    const float4* bc = (const float4*)(sBC + i * 32);
    float4 B0 = bc[0], B1 = bc[1], B2 = bc[2], B3 = bc[3];
    float Bv[16] = {B0.x,B0.y,B0.z,B0.w, B1.x,B1.y,B1.z,B1.w,
                    B2.x,B2.y,B2.z,B2.w, B3.x,B3.y,B3.z,B3.w};
    #pragma unroll
    for (int s = 0; s < 16; s++) {
      float dA = __expf(dlt * a[s]);
      h[s] = dA * h[s] + dlt * Bv[s];
      p[s] *= dA;
    }
  }
  size_t o = (size_t)chunk * SEQS + ((size_t)b * DI + d) * 16;
  #pragma unroll
  for (int s = 0; s < 16; s += 4) {
    ((float4*)(prodA + o))[s >> 2] = make_float4(p[s], p[s+1], p[s+2], p[s+3]);
    ((float4*)(hend  + o))[s >> 2] = make_float4(h[s], h[s+1], h[s+2], h[s+3]);
  }
}

__global__ __launch_bounds__(64) void scan_comb_k(const float* __restrict__ prodA,
                                                  const float* __restrict__ hend,
                                                  float* __restrict__ hstart) {
  int idx = blockIdx.x * 64 + threadIdx.x;   // 0 .. SEQS-1
  float run = 0.f;
  #pragma unroll
  for (int c = 0; c < NCH; c++) {
    size_t o = (size_t)c * SEQS + idx;
    hstart[o] = run;
    run = prodA[o] * run + hend[o];
  }
}

__global__ __launch_bounds__(64) void scan_fin_k(const float* __restrict__ delta,
                                                 const float* __restrict__ xdbl,
                                                 const float* __restrict__ A_log,
                                                 const float* __restrict__ Dp,
                                                 const float* __restrict__ xc,
                                                 const float* __restrict__ z,
                                                 const float* __restrict__ hstart,
                                                 __hip_bfloat16* __restrict__ ypbf) {
  __shared__ float sBC[CHL * 32];
  const int t = threadIdx.x;
  const int dg = blockIdx.x % (DI / 64);
  const int chunk = (blockIdx.x / (DI / 64)) % NCH;
  const int b = blockIdx.x / ((DI / 64) * NCH);
  const int d = dg * 64 + t;

  float a[16];
  #pragma unroll
  for (int s = 0; s < 16; s++) a[s] = -__expf(A_log[s]);

  const float4* src = (const float4*)(xdbl + ((size_t)b * LL + chunk * CHL) * 32);
  #pragma unroll
  for (int k = 0; k < 8; k++) ((float4*)sBC)[t + k * 64] = src[t + k * 64];
  __syncthreads();

  float h[16];
  size_t o = (size_t)chunk * SEQS + ((size_t)b * DI + d) * 16;
  #pragma unroll
  for (int s = 0; s < 16; s += 4) {
    float4 v = ((const float4*)(hstart + o))[s >> 2];
    h[s] = v.x; h[s+1] = v.y; h[s+2] = v.z; h[s+3] = v.w;
  }
  const float Dv = Dp[d];

  const size_t rbase = (size_t)b * LL + chunk * CHL;
  const float* dptr = delta + rbase * DI + d;
  const float* xcp  = xc    + rbase * DI + d;
  const float* zp   = z     + rbase * DI + d;
  __hip_bfloat16* yp = ypbf + rbase * DI + d;

  #pragma unroll 2
  for (int i = 0; i < CHL; i++) {
    float dlt = dptr[(size_t)i * DI];
    const float4* bc = (const float4*)(sBC + i * 32);
    float4 B0 = bc[0], B1 = bc[1], B2 = bc[2], B3 = bc[3];
    float4 C0 = bc[4], C1 = bc[5], C2 = bc[6], C3 = bc[7];
    float Bv[16] = {B0.x,B0.y,B0.z,B0.w, B1.x,B1.y,B1.z,B1.w,
                    B2.x,B2.y,B2.z,B2.w, B3.x,B3.y,B3.z,B3.w};
    float Cv[16] = {C0.x,C0.y,C0.z,C0.w, C1.x,C1.y,C1.z,C1.w,
                    C2.x,C2.y,C2.z,C2.w, C3.x,C3.y,C3.z,C3.w};
    float y = 0.f;
    #pragma unroll
    for (int s = 0; s < 16; s++) {
      float dA = __expf(dlt * a[s]);
      h[s] = dA * h[s] + dlt * Bv[s];
      y += h[s] * Cv[s];
    }
    float xcv = xcp[(size_t)i * DI];
    float zv  = zp [(size_t)i * DI];
    float val = (y + Dv * xcv) * (zv / (1.f + __expf(-zv)));
    yp[(size_t)i * DI] = __float2bfloat16(val);
  }
}

extern "C" void kernel_launch(void* const* d_in, const int* in_sizes, int n_in,
                              void* d_out, int out_size, void* d_ws, size_t ws_size,
                              hipStream_t stream) {
  const float* x      = (const float*)d_in[0];
  const float* W_in   = (const float*)d_in[1];
  const float* W_conv = (const float*)d_in[2];
  const float* W_x    = (const float*)d_in[3];
  const float* W_dt   = (const float*)d_in[4];
  const float* b_dt   = (const float*)d_in[5];
  const float* A_log  = (const float*)d_in[6];
  const float* Dp     = (const float*)d_in[7];
  const float* W_out  = (const float*)d_in[8];
  float* out = (float*)d_out;

  char* ws = (char*)d_ws;
  // workspace layout (bytes), total 144441344
  float*          xpart  = (float*)(ws + 0);                         // 25165824
  float*          z      = (float*)(ws + 25165824);                  // 25165824
  __hip_bfloat16* xbf    = (__hip_bfloat16*)(ws + 50331648);         // 6291456 (dead after GEMM1)
  __hip_bfloat16* Winbf  = (__hip_bfloat16*)(ws + 56623104);         // 4718592
  float*          xc     = (float*)(ws + 61341696);                  // 25165824
  __hip_bfloat16* xcbf   = (__hip_bfloat16*)(ws + 86507520);         // 12582912
  float*          delta  = (float*)(ws + 103809024);                 // 25165824
  float*          xdbl   = (float*)(ws + 128974848);                 // 524288
  __hip_bfloat16* ypbf   = (__hip_bfloat16*)(ws + 129499136);        // 12582912
  __hip_bfloat16* Woutbf = (__hip_bfloat16*)(ws + 142082048);        // 2359296
  // aliases of dead regions:
  float*          prodA  = (float*)(ws + 0);                         // xpart region (dead after conv)
  float*          hend   = (float*)(ws + 6291456);
  float*          hstart = (float*)(ws + 12582912);
  __hip_bfloat16* Wcomb  = (__hip_bfloat16*)(ws + 50331648);         // xbf region: 1664*1536*2 = 5111808

  // fp32 -> bf16 converts
  cvt4_k<<<(786432 + 255) / 256, 256, 0, stream>>>(x, xbf, 786432);
  cvt4_k<<<(589824 + 255) / 256, 256, 0, stream>>>(W_in, Winbf, 589824);
  cvt4_k<<<(294912 + 255) / 256, 256, 0, stream>>>(W_out, Woutbf, 294912);

  // xz = x @ W_in.T (4096 x 3072, K=768), split-stored into xpart | z
  {
    dim3 g(3072 / 64, 4096 / 64);     // 3072 blocks (1 wave each)
    gemm_w<2, DM><<<g, 64, 0, stream>>>(xbf, Winbf, xpart, z, nullptr, 2 * DI);
  }
  // xc = silu(causal_dwconv(xpart))
  conv_silu_k<<<(MM * DI + 255) / 256, 256, 0, stream>>>(xpart, W_conv, xc, xcbf);
  // Wcomb = [W_dt ; W_x ; 0] bf16 (aliases xbf, dead after GEMM1)
  wcomb_k<<<(NC2 * DI / 4 + 255) / 256, 256, 0, stream>>>(W_dt, W_x, Wcomb);
  // delta = softplus(xc @ W_dt.T + b_dt) AND xdbl = xc @ W_x.T, one GEMM (N=1664)
  {
    dim3 g(NC2 / 64, 4096 / 64);      // 1664 blocks
    gemm_w<3, DI><<<g, 64, 0, stream>>>(xcbf, Wcomb, delta, xdbl, b_dt, NC2);
  }
  // chunked selective scan + gating
  scan_part_k<<<BB * NCH * (DI / 64), 64, 0, stream>>>(delta, xdbl, A_log, prodA, hend);
  scan_comb_k<<<SEQS / 64, 64, 0, stream>>>(prodA, hend, hstart);
  scan_fin_k<<<BB * NCH * (DI / 64), 64, 0, stream>>>(delta, xdbl, A_log, Dp, xc, z,
                                                      hstart, ypbf);
  // out = y @ W_out.T (4096 x 768, K=1536)
  {
    dim3 g(768 / 64, 4096 / 64);      // 768 blocks
    gemm_w<0, DI><<<g, 64, 0, stream>>>(ypbf, Woutbf, out, nullptr, nullptr, DM);
  }
}

// Round 8
// 417.842 us; speedup vs baseline: 1.0405x; 1.0405x over previous
//
#include <hip/hip_runtime.h>
#include <hip/hip_bf16.h>

// Problem constants (B=2, L=2048, Dm=768, di=1536, ds=16, dc=4)
#define BB 2
#define LL 2048
#define DM 768
#define DI 1536
#define DS 16
#define MM (BB*LL)   // 4096 rows
#define NCH 32       // scan chunks
#define CHL 64       // steps per chunk
#define SEQS (BB*DI*DS)  // 49152 independent scalar recurrences
#define NC2 1664     // delta GEMM fused N: 1536 (W_dt) + 32 (W_x) + 96 pad

typedef __hip_bfloat16 bf16;
typedef short bf16x8 __attribute__((ext_vector_type(8)));
typedef float f32x4  __attribute__((ext_vector_type(4)));

__device__ __forceinline__ void gl_lds16(const void* g, void* l) {
  __builtin_amdgcn_global_load_lds((const __attribute__((address_space(1))) void*)g,
                                   (__attribute__((address_space(3))) void*)l, 16, 0, 0);
}

// ---------------- zero-init (outputs are poisoned 0xAA by harness) ----------------
__global__ void zero_k(float4* __restrict__ p, int n4) {
  int i = blockIdx.x * 256 + threadIdx.x;
  if (i < n4) p[i] = make_float4(0.f, 0.f, 0.f, 0.f);
}

// ---------------- fp32 -> bf16 convert (4 elems/thread) ----------------
struct bf4 { __hip_bfloat16 a, b, c, d; };
__global__ void cvt4_k(const float* __restrict__ in, __hip_bfloat16* __restrict__ out, int n4) {
  int i = blockIdx.x * 256 + threadIdx.x;
  if (i < n4) {
    float4 v = ((const float4*)in)[i];
    bf4 o = { __float2bfloat16(v.x), __float2bfloat16(v.y),
              __float2bfloat16(v.z), __float2bfloat16(v.w) };
    ((bf4*)out)[i] = o;
  }
}

// ---------------- build Wcomb[1664][1536] bf16 = [W_dt ; W_x ; 0-pad] ----------------
__global__ void wcomb_k(const float* __restrict__ Wdt, const float* __restrict__ Wx,
                        __hip_bfloat16* __restrict__ out) {
  int i = blockIdx.x * 256 + threadIdx.x;          // one float4 per thread
  if (i >= NC2 * DI / 4) return;
  int e = i * 4;
  int row = e / DI, colb = e % DI;
  float4 v;
  if (row < DI)            v = ((const float4*)Wdt)[i];
  else if (row < DI + 32)  v = *(const float4*)(Wx + (size_t)(row - DI) * DI + colb);
  else                     v = make_float4(0.f, 0.f, 0.f, 0.f);
  bf4 o = { __float2bfloat16(v.x), __float2bfloat16(v.y),
            __float2bfloat16(v.z), __float2bfloat16(v.w) };
  ((bf4*)out)[i] = o;
}

// ---------------- pipelined NT bf16 MFMA GEMM, 128x128 tile (R5 structure) ----------
// C[M,N] = A[M,K] * W[N,K]^T, optionally split-K over blockIdx.z (Kext cols each).
// 256 threads = 4 waves (2x2), wave tile 64x64 (16 MFMA/iter). Staging:
// global_load_lds width=16 (no VGPR transit). 3 LDS buffers, 2 tiles in flight,
// ONE barrier/iter: s_waitcnt vmcnt(NPW) + s_barrier (loads stay in flight).
// Loads for tile i+2 issued AFTER barrier i (WAR-safe: ds_reads of that buffer
// were value-dep drained before barrier i-? -- see R5 proof).
// EPI: 2 = split store: col<DI -> C (stride DI), else -> C2 (stride DI) [xz GEMM]
//      3 = split ATOMIC partials: col<DI -> +=C (stride DI, raw pre-softplus);
//          col in [DI,DI+32) -> +=C2 (stride 32); else discard       [delta+xdbl]
//      4 = plain ATOMIC: C[row*N+col] += v                           [out GEMM]
template<int EPI>
__global__ __launch_bounds__(256) void gemm_db(const bf16* __restrict__ A,
                                               const bf16* __restrict__ W,
                                               float* __restrict__ C,
                                               float* __restrict__ C2,
                                               int M, int N, int Kstride, int Kext) {
  constexpr int NPW = 4;              // gl_lds per wave per tile (2 A + 2 B)
  __shared__ short sA[3][128 * 32];
  __shared__ short sB[3][128 * 32];
  const int t = threadIdx.x;
  const int m0 = blockIdx.y * 128, n0 = blockIdx.x * 128;
  const size_t koff = (size_t)blockIdx.z * Kext;
  const int w = t >> 6, lane = t & 63;
  const int wm = (w >> 1) * 64, wn = (w & 1) * 64;
  const int ga = wm >> 4, gb = wn >> 4;

  f32x4 acc[2][4] = {};   // wave 64x64: 4 m-blocks x 4 n-blocks... (2x f32x4 rows per m)
  f32x4 acc2[2][4] = {};  // split to keep the R5 register shape: acc[i], acc2[i] = m-blocks 0..3

  // wave w stages A row-blocks {w, w+4}, B row-blocks {w, w+4};
  // dest = wave-uniform base, lane-linear (frag idx == lane).
  const int srow = lane & 15, skoff = (lane >> 4) * 8;
  const bf16* gA[2]; const bf16* gB[2];
  #pragma unroll
  for (int j = 0; j < 2; j++)
    gA[j] = A + (size_t)(m0 + (w + 4 * j) * 16 + srow) * Kstride + koff + skoff;
  #pragma unroll
  for (int j = 0; j < 2; j++)
    gB[j] = W + (size_t)(n0 + (w + 4 * j) * 16 + srow) * Kstride + koff + skoff;

  #define ISSUE(buf, k0)                                              \
    do {                                                              \
      _Pragma("unroll")                                               \
      for (int j = 0; j < 2; j++)                                     \
        gl_lds16(gA[j] + (k0), &sA[buf][(w + 4 * j) * 512]);          \
      _Pragma("unroll")                                               \
      for (int j = 0; j < 2; j++)                                     \
        gl_lds16(gB[j] + (k0), &sB[buf][(w + 4 * j) * 512]);          \
    } while (0)

  ISSUE(0, 0);
  ISSUE(1, 32);
  int p = 0;
  for (int k0 = 0; k0 < Kext; k0 += 32) {
    if (k0 + 32 < Kext) {
      asm volatile("s_waitcnt vmcnt(%0)\n\ts_barrier" :: "n"(NPW) : "memory");
    } else {
      asm volatile("s_waitcnt vmcnt(0)\n\ts_barrier" ::: "memory");
    }
    if (k0 + 64 < Kext) {
      int nb = p + 2; if (nb >= 3) nb -= 3;
      ISSUE(nb, k0 + 64);
    }
    const bf16x8* fA = (const bf16x8*)sA[p];
    const bf16x8* fB = (const bf16x8*)sB[p];
    bf16x8 af[4], bfr[4];
    #pragma unroll
    for (int i = 0; i < 4; i++) af[i]  = fA[(ga + i) * 64 + lane];
    #pragma unroll
    for (int j = 0; j < 4; j++) bfr[j] = fB[(gb + j) * 64 + lane];
    #pragma unroll
    for (int i = 0; i < 2; i++)
      #pragma unroll
      for (int j = 0; j < 4; j++)
        acc[i][j] = __builtin_amdgcn_mfma_f32_16x16x32_bf16(af[i], bfr[j], acc[i][j], 0, 0, 0);
    #pragma unroll
    for (int i = 0; i < 2; i++)
      #pragma unroll
      for (int j = 0; j < 4; j++)
        acc2[i][j] = __builtin_amdgcn_mfma_f32_16x16x32_bf16(af[i + 2], bfr[j], acc2[i][j], 0, 0, 0);
    p++; if (p >= 3) p = 0;
  }
  #undef ISSUE

  const int q = lane >> 4, mm = lane & 15;
  #pragma unroll
  for (int ii = 0; ii < 4; ii++)
    #pragma unroll
    for (int j = 0; j < 4; j++) {
      int r0  = m0 + wm + ii * 16 + q * 4;
      int col = n0 + wn + j * 16 + mm;
      #pragma unroll
      for (int r = 0; r < 4; r++) {
        float v = (ii < 2) ? acc[ii][j][r] : acc2[ii - 2][j][r];
        if (EPI == 2) {
          if (col < DI) C [(size_t)(r0 + r) * DI + col]        = v;
          else          C2[(size_t)(r0 + r) * DI + (col - DI)] = v;
        } else if (EPI == 3) {
          if (col < DI)           atomicAdd(&C [(size_t)(r0 + r) * DI + col], v);
          else if (col < DI + 32) atomicAdd(&C2[(size_t)(r0 + r) * 32 + (col - DI)], v);
        } else {  // EPI == 4
          atomicAdd(&C[(size_t)(r0 + r) * N + col], v);
        }
      }
    }
}

// ---------------- depthwise causal conv (dc=4) + SiLU; writes fp32 + bf16 ----------------
__global__ __launch_bounds__(256) void conv_silu_k(const float* __restrict__ xpart,
                                                   const float* __restrict__ Wc,
                                                   float* __restrict__ xc,
                                                   __hip_bfloat16* __restrict__ xcbf) {
  int idx = blockIdx.x * 256 + threadIdx.x;
  if (idx >= MM * DI) return;
  int d = idx % DI;
  int r = idx / DI;
  int l = r & (LL - 1);
  float4 wv = ((const float4*)Wc)[d];  // W_conv[d, 0, 0..3]
  const float* xp = xpart + (size_t)r * DI + d;
  float acc = wv.w * xp[0];
  if (l >= 1) acc += wv.z * xp[-(ptrdiff_t)DI];
  if (l >= 2) acc += wv.y * xp[-(ptrdiff_t)(2 * DI)];
  if (l >= 3) acc += wv.x * xp[-(ptrdiff_t)(3 * DI)];
  float s = acc / (1.f + __expf(-acc));   // silu
  xc[idx] = s;
  xcbf[idx] = __float2bfloat16(s);
}

// ================= chunked selective scan =================
// delta buffer now holds RAW GEMM output (pre bias/softplus); scan applies
// dlt = softplus(raw + b_dt[d]) inline (idle VALU in these latency-bound kernels).
__device__ __forceinline__ float sp_f(float v) {
  return (v > 15.f) ? v : __logf(1.f + __expf(v));
}

__global__ __launch_bounds__(64) void scan_part_k(const float* __restrict__ delta,
                                                  const float* __restrict__ xdbl,
                                                  const float* __restrict__ A_log,
                                                  const float* __restrict__ bdt,
                                                  float* __restrict__ prodA,
                                                  float* __restrict__ hend) {
  __shared__ float sBC[CHL * 32];
  const int t = threadIdx.x;
  const int dg = blockIdx.x % (DI / 64);
  const int chunk = (blockIdx.x / (DI / 64)) % NCH;
  const int b = blockIdx.x / ((DI / 64) * NCH);
  const int d = dg * 64 + t;

  float a[16];
  #pragma unroll
  for (int s = 0; s < 16; s++) a[s] = -__expf(A_log[s]);
  const float bd = bdt[d];

  const float4* src = (const float4*)(xdbl + ((size_t)b * LL + chunk * CHL) * 32);
  #pragma unroll
  for (int k = 0; k < 8; k++) ((float4*)sBC)[t + k * 64] = src[t + k * 64];
  __syncthreads();

  float h[16], p[16];
  #pragma unroll
  for (int s = 0; s < 16; s++) { h[s] = 0.f; p[s] = 1.f; }

  const float* dptr = delta + ((size_t)b * LL + chunk * CHL) * DI + d;
  #pragma unroll 2
  for (int i = 0; i < CHL; i++) {
    float dlt = sp_f(dptr[(size_t)i * DI] + bd);
    const float4* bc = (const float4*)(sBC + i * 32);
    float4 B0 = bc[0], B1 = bc[1], B2 = bc[2], B3 = bc[3];
    float Bv[16] = {B0.x,B0.y,B0.z,B0.w, B1.x,B1.y,B1.z,B1.w,
                    B2.x,B2.y,B2.z,B2.w, B3.x,B3.y,B3.z,B3.w};
    #pragma unroll
    for (int s = 0; s < 16; s++) {
      float dA = __expf(dlt * a[s]);
      h[s] = dA * h[s] + dlt * Bv[s];
      p[s] *= dA;
    }
  }
  size_t o = (size_t)chunk * SEQS + ((size_t)b * DI + d) * 16;
  #pragma unroll
  for (int s = 0; s < 16; s += 4) {
    ((float4*)(prodA + o))[s >> 2] = make_float4(p[s], p[s+1], p[s+2], p[s+3]);
    ((float4*)(hend  + o))[s >> 2] = make_float4(h[s], h[s+1], h[s+2], h[s+3]);
  }
}

__global__ __launch_bounds__(64) void scan_comb_k(const float* __restrict__ prodA,
                                                  const float* __restrict__ hend,
                                                  float* __restrict__ hstart) {
  int idx = blockIdx.x * 64 + threadIdx.x;   // 0 .. SEQS-1
  float run = 0.f;
  #pragma unroll
  for (int c = 0; c < NCH; c++) {
    size_t o = (size_t)c * SEQS + idx;
    hstart[o] = run;
    run = prodA[o] * run + hend[o];
  }
}

__global__ __launch_bounds__(64) void scan_fin_k(const float* __restrict__ delta,
                                                 const float* __restrict__ xdbl,
                                                 const float* __restrict__ A_log,
                                                 const float* __restrict__ bdt,
                                                 const float* __restrict__ Dp,
                                                 const float* __restrict__ xc,
                                                 const float* __restrict__ z,
                                                 const float* __restrict__ hstart,
                                                 __hip_bfloat16* __restrict__ ypbf) {
  __shared__ float sBC[CHL * 32];
  const int t = threadIdx.x;
  const int dg = blockIdx.x % (DI / 64);
  const int chunk = (blockIdx.x / (DI / 64)) % NCH;
  const int b = blockIdx.x / ((DI / 64) * NCH);
  const int d = dg * 64 + t;

  float a[16];
  #pragma unroll
  for (int s = 0; s < 16; s++) a[s] = -__expf(A_log[s]);
  const float bd = bdt[d];

  const float4* src = (const float4*)(xdbl + ((size_t)b * LL + chunk * CHL) * 32);
  #pragma unroll
  for (int k = 0; k < 8; k++) ((float4*)sBC)[t + k * 64] = src[t + k * 64];
  __syncthreads();

  float h[16];
  size_t o = (size_t)chunk * SEQS + ((size_t)b * DI + d) * 16;
  #pragma unroll
  for (int s = 0; s < 16; s += 4) {
    float4 v = ((const float4*)(hstart + o))[s >> 2];
    h[s] = v.x; h[s+1] = v.y; h[s+2] = v.z; h[s+3] = v.w;
  }
  const float Dv = Dp[d];

  const size_t rbase = (size_t)b * LL + chunk * CHL;
  const float* dptr = delta + rbase * DI + d;
  const float* xcp  = xc    + rbase * DI + d;
  const float* zp   = z     + rbase * DI + d;
  __hip_bfloat16* yp = ypbf + rbase * DI + d;

  #pragma unroll 2
  for (int i = 0; i < CHL; i++) {
    float dlt = sp_f(dptr[(size_t)i * DI] + bd);
    const float4* bc = (const float4*)(sBC + i * 32);
    float4 B0 = bc[0], B1 = bc[1], B2 = bc[2], B3 = bc[3];
    float4 C0 = bc[4], C1 = bc[5], C2 = bc[6], C3 = bc[7];
    float Bv[16] = {B0.x,B0.y,B0.z,B0.w, B1.x,B1.y,B1.z,B1.w,
                    B2.x,B2.y,B2.z,B2.w, B3.x,B3.y,B3.z,B3.w};
    float Cv[16] = {C0.x,C0.y,C0.z,C0.w, C1.x,C1.y,C1.z,C1.w,
                    C2.x,C2.y,C2.z,C2.w, C3.x,C3.y,C3.z,C3.w};
    float y = 0.f;
    #pragma unroll
    for (int s = 0; s < 16; s++) {
      float dA = __expf(dlt * a[s]);
      h[s] = dA * h[s] + dlt * Bv[s];
      y += h[s] * Cv[s];
    }
    float xcv = xcp[(size_t)i * DI];
    float zv  = zp [(size_t)i * DI];
    float val = (y + Dv * xcv) * (zv / (1.f + __expf(-zv)));
    yp[(size_t)i * DI] = __float2bfloat16(val);
  }
}

extern "C" void kernel_launch(void* const* d_in, const int* in_sizes, int n_in,
                              void* d_out, int out_size, void* d_ws, size_t ws_size,
                              hipStream_t stream) {
  const float* x      = (const float*)d_in[0];
  const float* W_in   = (const float*)d_in[1];
  const float* W_conv = (const float*)d_in[2];
  const float* W_x    = (const float*)d_in[3];
  const float* W_dt   = (const float*)d_in[4];
  const float* b_dt   = (const float*)d_in[5];
  const float* A_log  = (const float*)d_in[6];
  const float* Dp     = (const float*)d_in[7];
  const float* W_out  = (const float*)d_in[8];
  float* out = (float*)d_out;

  char* ws = (char*)d_ws;
  // workspace layout (bytes), total 144441344
  float*          xpart  = (float*)(ws + 0);                         // 25165824
  float*          z      = (float*)(ws + 25165824);                  // 25165824
  __hip_bfloat16* xbf    = (__hip_bfloat16*)(ws + 50331648);         // 6291456 (dead after GEMM1)
  __hip_bfloat16* Winbf  = (__hip_bfloat16*)(ws + 56623104);         // 4718592
  float*          xc     = (float*)(ws + 61341696);                  // 25165824
  __hip_bfloat16* xcbf   = (__hip_bfloat16*)(ws + 86507520);         // 12582912
  float*          delta  = (float*)(ws + 103809024);                 // 25165824 (raw partial sums)
  float*          xdbl   = (float*)(ws + 128974848);                 // 524288
  __hip_bfloat16* ypbf   = (__hip_bfloat16*)(ws + 129499136);        // 12582912
  __hip_bfloat16* Woutbf = (__hip_bfloat16*)(ws + 142082048);        // 2359296
  // aliases of dead regions:
  float*          prodA  = (float*)(ws + 0);                         // xpart region (dead after conv)
  float*          hend   = (float*)(ws + 6291456);
  float*          hstart = (float*)(ws + 12582912);
  __hip_bfloat16* Wcomb  = (__hip_bfloat16*)(ws + 50331648);         // xbf region: 1664*1536*2

  // zero split-K accumulation targets (poisoned 0xAA before every launch)
  zero_k<<<(1572864 + 255) / 256, 256, 0, stream>>>((float4*)delta, 1572864);  // 25.2 MB
  zero_k<<<(32768   + 255) / 256, 256, 0, stream>>>((float4*)xdbl,  32768);
  zero_k<<<(786432  + 255) / 256, 256, 0, stream>>>((float4*)out,   786432);   // 12.6 MB

  // fp32 -> bf16 converts
  cvt4_k<<<(786432 + 255) / 256, 256, 0, stream>>>(x, xbf, 786432);
  cvt4_k<<<(589824 + 255) / 256, 256, 0, stream>>>(W_in, Winbf, 589824);
  cvt4_k<<<(294912 + 255) / 256, 256, 0, stream>>>(W_out, Woutbf, 294912);

  // xz = x @ W_in.T (4096 x 3072, K=768), split-stored into xpart | z
  {
    dim3 g(3072 / 128, 4096 / 128, 1);   // 768 blocks (3/CU, at LDS cap)
    gemm_db<2><<<g, 256, 0, stream>>>(xbf, Winbf, xpart, z, MM, 2 * DI, DM, DM);
  }
  // xc = silu(causal_dwconv(xpart))
  conv_silu_k<<<(MM * DI + 255) / 256, 256, 0, stream>>>(xpart, W_conv, xc, xcbf);
  // Wcomb = [W_dt ; W_x ; 0] bf16 (aliases xbf, dead after GEMM1)
  wcomb_k<<<(NC2 * DI / 4 + 255) / 256, 256, 0, stream>>>(W_dt, W_x, Wcomb);
  // delta_raw += xc @ W_dt.T partials AND xdbl += xc @ W_x.T, split-K=2 (832 blocks)
  {
    dim3 g(NC2 / 128, 4096 / 128, 2);
    gemm_db<3><<<g, 256, 0, stream>>>(xcbf, Wcomb, delta, xdbl, MM, NC2, DI, DI / 2);
  }
  // chunked selective scan + gating (softplus(raw+b_dt) applied inline)
  scan_part_k<<<BB * NCH * (DI / 64), 64, 0, stream>>>(delta, xdbl, A_log, b_dt, prodA, hend);
  scan_comb_k<<<SEQS / 64, 64, 0, stream>>>(prodA, hend, hstart);
  scan_fin_k<<<BB * NCH * (DI / 64), 64, 0, stream>>>(delta, xdbl, A_log, b_dt, Dp, xc, z,
                                                      hstart, ypbf);
  // out += y @ W_out.T, split-K=4 (768 blocks, 128x128 density-16 tiles)
  {
    dim3 g(768 / 128, 4096 / 128, 4);
    gemm_db<4><<<g, 256, 0, stream>>>(ypbf, Woutbf, out, nullptr, MM, DM, DI, DI / 4);
  }
}

// Round 9
// 396.180 us; speedup vs baseline: 1.0974x; 1.0547x over previous
//
#include <hip/hip_runtime.h>
#include <hip/hip_bf16.h>

// Problem constants (B=2, L=2048, Dm=768, di=1536, ds=16, dc=4)
#define BB 2
#define LL 2048
#define DM 768
#define DI 1536
#define DS 16
#define MM (BB*LL)   // 4096 rows
#define NCH 32       // scan chunks
#define CHL 64       // steps per chunk
#define SEQS (BB*DI*DS)  // 49152 independent scalar recurrences
#define NC2 1664     // delta GEMM fused N: 1536 (W_dt) + 32 (W_x) + 96 pad

typedef __hip_bfloat16 bf16;
typedef short bf16x8 __attribute__((ext_vector_type(8)));
typedef float f32x4  __attribute__((ext_vector_type(4)));

__device__ __forceinline__ void gl_lds16(const void* g, void* l) {
  __builtin_amdgcn_global_load_lds((const __attribute__((address_space(1))) void*)g,
                                   (__attribute__((address_space(3))) void*)l, 16, 0, 0);
}

// ---------------- fp32 -> bf16 convert (4 elems/thread) ----------------
struct bf4 { __hip_bfloat16 a, b, c, d; };
__global__ void cvt4_k(const float* __restrict__ in, __hip_bfloat16* __restrict__ out, int n4) {
  int i = blockIdx.x * 256 + threadIdx.x;
  if (i < n4) {
    float4 v = ((const float4*)in)[i];
    bf4 o = { __float2bfloat16(v.x), __float2bfloat16(v.y),
              __float2bfloat16(v.z), __float2bfloat16(v.w) };
    ((bf4*)out)[i] = o;
  }
}

// ---------------- build Wcomb[1664][1536] bf16 = [W_dt ; W_x ; 0-pad] ----------------
__global__ void wcomb_k(const float* __restrict__ Wdt, const float* __restrict__ Wx,
                        __hip_bfloat16* __restrict__ out) {
  int i = blockIdx.x * 256 + threadIdx.x;          // one float4 per thread
  if (i >= NC2 * DI / 4) return;
  int e = i * 4;
  int row = e / DI, colb = e % DI;
  float4 v;
  if (row < DI)            v = ((const float4*)Wdt)[i];
  else if (row < DI + 32)  v = *(const float4*)(Wx + (size_t)(row - DI) * DI + colb);
  else                     v = make_float4(0.f, 0.f, 0.f, 0.f);
  bf4 o = { __float2bfloat16(v.x), __float2bfloat16(v.y),
            __float2bfloat16(v.z), __float2bfloat16(v.w) };
  ((bf4*)out)[i] = o;
}

// ---------------- R5 pipelined LDS-staged GEMM (proven 359us config) ----------------
// EPI: 0 = plain fp32 store (stride N)
//      2 = split: col<DI -> C (stride DI), else -> C2 (stride DI)   [xz GEMM]
template<int EPI, int BM>
__global__ __launch_bounds__(256) void gemm_db(const bf16* __restrict__ A,
                                               const bf16* __restrict__ W,
                                               float* __restrict__ C,
                                               float* __restrict__ C2,
                                               const float* __restrict__ bias,
                                               int M, int N, int K) {
  constexpr int NA  = BM / 64;
  constexpr int NPW = NA + 2;
  __shared__ short sA[3][BM * 32];
  __shared__ short sB[3][128 * 32];
  const int t = threadIdx.x;
  const int m0 = blockIdx.y * BM, n0 = blockIdx.x * 128;
  const int w = t >> 6, lane = t & 63;
  const int wm = (w >> 1) * (BM / 2), wn = (w & 1) * 64;
  const int ga = wm >> 4, gb = wn >> 4;

  f32x4 acc[BM / 32][4] = {};

  const int srow = lane & 15, skoff = (lane >> 4) * 8;
  const bf16* gA[NA]; const bf16* gB[2];
  #pragma unroll
  for (int j = 0; j < NA; j++)
    gA[j] = A + (size_t)(m0 + (w + 4 * j) * 16 + srow) * K + skoff;
  #pragma unroll
  for (int j = 0; j < 2; j++)
    gB[j] = W + (size_t)(n0 + (w + 4 * j) * 16 + srow) * K + skoff;

  #define ISSUE(buf, k0)                                              \
    do {                                                              \
      _Pragma("unroll")                                               \
      for (int j = 0; j < NA; j++)                                    \
        gl_lds16(gA[j] + (k0), &sA[buf][(w + 4 * j) * 512]);          \
      _Pragma("unroll")                                               \
      for (int j = 0; j < 2; j++)                                     \
        gl_lds16(gB[j] + (k0), &sB[buf][(w + 4 * j) * 512]);          \
    } while (0)

  ISSUE(0, 0);
  ISSUE(1, 32);
  int p = 0;
  for (int k0 = 0; k0 < K; k0 += 32) {
    if (k0 + 32 < K) {
      asm volatile("s_waitcnt vmcnt(%0)\n\ts_barrier" :: "n"(NPW) : "memory");
    } else {
      asm volatile("s_waitcnt vmcnt(0)\n\ts_barrier" ::: "memory");
    }
    if (k0 + 64 < K) {
      int nb = p + 2; if (nb >= 3) nb -= 3;
      ISSUE(nb, k0 + 64);
    }
    const bf16x8* fA = (const bf16x8*)sA[p];
    const bf16x8* fB = (const bf16x8*)sB[p];
    bf16x8 af[BM / 32], bfr[4];
    #pragma unroll
    for (int i = 0; i < BM / 32; i++) af[i]  = fA[(ga + i) * 64 + lane];
    #pragma unroll
    for (int j = 0; j < 4; j++)       bfr[j] = fB[(gb + j) * 64 + lane];
    #pragma unroll
    for (int i = 0; i < BM / 32; i++)
      #pragma unroll
      for (int j = 0; j < 4; j++)
        acc[i][j] = __builtin_amdgcn_mfma_f32_16x16x32_bf16(af[i], bfr[j], acc[i][j], 0, 0, 0);
    p++; if (p >= 3) p = 0;
  }
  #undef ISSUE

  const int q = lane >> 4, mm = lane & 15;
  #pragma unroll
  for (int i = 0; i < BM / 32; i++)
    #pragma unroll
    for (int j = 0; j < 4; j++) {
      int r0  = m0 + wm + i * 16 + q * 4;
      int col = n0 + wn + j * 16 + mm;
      #pragma unroll
      for (int r = 0; r < 4; r++) {
        float v = acc[i][j][r];
        if (EPI == 0) {
          C[(size_t)(r0 + r) * N + col] = v;
        } else {  // EPI == 2
          if (col < DI) C [(size_t)(r0 + r) * DI + col]        = v;
          else          C2[(size_t)(r0 + r) * DI + (col - DI)] = v;
        }
      }
    }
}

// ---------------- LDS-free direct-fragment GEMM (AITER-style K-loop) -------------
// C[M,N] = A[M,K]*W[N,K]^T. 256 threads = 4 waves 2x2, wave tile 64x64. Fragments
// load straight global->VGPR (pattern row=lane&15, k=(lane>>4)*8 is 16 full 64B
// lines -> fully coalesced), register double-buffered, NO LDS, NO barriers.
// Loads for chunk c+1 are issued before MFMAs of chunk c -> compiler emits
// s_waitcnt vmcnt(8) (never 0) between load block and MFMA block.
// K templated (multiple of 64). EPI 3 = delta+xdbl split epilogue.
template<int EPI, int K>
__global__ __launch_bounds__(256) void gemm_df(const bf16* __restrict__ A,
                                               const bf16* __restrict__ W,
                                               float* __restrict__ C,
                                               float* __restrict__ C2,
                                               const float* __restrict__ bias,
                                               int N) {
  const int t = threadIdx.x;
  const int m0 = blockIdx.y * 128, n0 = blockIdx.x * 128;
  const int w = t >> 6, lane = t & 63;
  const int wm = (w >> 1) * 64, wn = (w & 1) * 64;
  const int row = lane & 15, kq = (lane >> 4) * 8;

  f32x4 acc[4][4] = {};

  const bf16* pA[4]; const bf16* pB[4];
  #pragma unroll
  for (int i = 0; i < 4; i++)
    pA[i] = A + (size_t)(m0 + wm + i * 16 + row) * K + kq;
  #pragma unroll
  for (int j = 0; j < 4; j++)
    pB[j] = W + (size_t)(n0 + wn + j * 16 + row) * K + kq;

  float4 fa0[4], fb0[4], fa1[4], fb1[4];
  #pragma unroll
  for (int i = 0; i < 4; i++) fa0[i] = *(const float4*)(pA[i]);
  #pragma unroll
  for (int j = 0; j < 4; j++) fb0[j] = *(const float4*)(pB[j]);

  #define MFMA_SET(fa, fb)                                                        \
    do {                                                                          \
      _Pragma("unroll")                                                           \
      for (int i = 0; i < 4; i++)                                                 \
        _Pragma("unroll")                                                         \
        for (int j = 0; j < 4; j++)                                               \
          acc[i][j] = __builtin_amdgcn_mfma_f32_16x16x32_bf16(                    \
              *(const bf16x8*)&fa[i], *(const bf16x8*)&fb[j], acc[i][j], 0,0,0);  \
    } while (0)

  #pragma unroll 1
  for (int k0 = 0; k0 < K; k0 += 64) {
    // prefetch chunk k0+32 into buf1, then consume buf0
    #pragma unroll
    for (int i = 0; i < 4; i++) fa1[i] = *(const float4*)(pA[i] + k0 + 32);
    #pragma unroll
    for (int j = 0; j < 4; j++) fb1[j] = *(const float4*)(pB[j] + k0 + 32);
    MFMA_SET(fa0, fb0);
    if (k0 + 64 < K) {
      #pragma unroll
      for (int i = 0; i < 4; i++) fa0[i] = *(const float4*)(pA[i] + k0 + 64);
      #pragma unroll
      for (int j = 0; j < 4; j++) fb0[j] = *(const float4*)(pB[j] + k0 + 64);
    }
    MFMA_SET(fa1, fb1);
  }
  #undef MFMA_SET

  const int q = lane >> 4, mm = lane & 15;
  #pragma unroll
  for (int i = 0; i < 4; i++)
    #pragma unroll
    for (int j = 0; j < 4; j++) {
      int r0  = m0 + wm + i * 16 + q * 4;
      int col = n0 + wn + j * 16 + mm;
      #pragma unroll
      for (int r = 0; r < 4; r++) {
        float v = acc[i][j][r];
        if (EPI == 3) {
          if (col < DI) {
            float vv = v + bias[col];
            vv = (vv > 15.f) ? vv : __logf(1.f + __expf(vv));
            C[(size_t)(r0 + r) * DI + col] = vv;
          } else if (col < DI + 32) {
            C2[(size_t)(r0 + r) * 32 + (col - DI)] = v;
          }
        } else {
          C[(size_t)(r0 + r) * N + col] = v;
        }
      }
    }
}

// ---------------- depthwise causal conv (dc=4) + SiLU; writes fp32 + bf16 ----------------
__global__ __launch_bounds__(256) void conv_silu_k(const float* __restrict__ xpart,
                                                   const float* __restrict__ Wc,
                                                   float* __restrict__ xc,
                                                   __hip_bfloat16* __restrict__ xcbf) {
  int idx = blockIdx.x * 256 + threadIdx.x;
  if (idx >= MM * DI) return;
  int d = idx % DI;
  int r = idx / DI;
  int l = r & (LL - 1);
  float4 wv = ((const float4*)Wc)[d];  // W_conv[d, 0, 0..3]
  const float* xp = xpart + (size_t)r * DI + d;
  float acc = wv.w * xp[0];
  if (l >= 1) acc += wv.z * xp[-(ptrdiff_t)DI];
  if (l >= 2) acc += wv.y * xp[-(ptrdiff_t)(2 * DI)];
  if (l >= 3) acc += wv.x * xp[-(ptrdiff_t)(3 * DI)];
  float s = acc / (1.f + __expf(-acc));   // silu
  xc[idx] = s;
  xcbf[idx] = __float2bfloat16(s);
}

// ================= chunked selective scan =================
__global__ __launch_bounds__(64) void scan_part_k(const float* __restrict__ delta,
                                                  const float* __restrict__ xdbl,
                                                  const float* __restrict__ A_log,
                                                  float* __restrict__ prodA,
                                                  float* __restrict__ hend) {
  __shared__ float sBC[CHL * 32];
  const int t = threadIdx.x;
  const int dg = blockIdx.x % (DI / 64);
  const int chunk = (blockIdx.x / (DI / 64)) % NCH;
  const int b = blockIdx.x / ((DI / 64) * NCH);
  const int d = dg * 64 + t;

  float a[16];
  #pragma unroll
  for (int s = 0; s < 16; s++) a[s] = -__expf(A_log[s]);

  const float4* src = (const float4*)(xdbl + ((size_t)b * LL + chunk * CHL) * 32);
  #pragma unroll
  for (int k = 0; k < 8; k++) ((float4*)sBC)[t + k * 64] = src[t + k * 64];
  __syncthreads();

  float h[16], p[16];
  #pragma unroll
  for (int s = 0; s < 16; s++) { h[s] = 0.f; p[s] = 1.f; }

  const float* dptr = delta + ((size_t)b * LL + chunk * CHL) * DI + d;
  #pragma unroll 2
  for (int i = 0; i < CHL; i++) {
    float dlt = dptr[(size_t)i * DI];
    const float4* bc = (const float4*)(sBC + i * 32);
    float4 B0 = bc[0], B1 = bc[1], B2 = bc[2], B3 = bc[3];
    float Bv[16] = {B0.x,B0.y,B0.z,B0.w, B1.x,B1.y,B1.z,B1.w,
                    B2.x,B2.y,B2.z,B2.w, B3.x,B3.y,B3.z,B3.w};
    #pragma unroll
    for (int s = 0; s < 16; s++) {
      float dA = __expf(dlt * a[s]);
      h[s] = dA * h[s] + dlt * Bv[s];
      p[s] *= dA;
    }
  }
  size_t o = (size_t)chunk * SEQS + ((size_t)b * DI + d) * 16;
  #pragma unroll
  for (int s = 0; s < 16; s += 4) {
    ((float4*)(prodA + o))[s >> 2] = make_float4(p[s], p[s+1], p[s+2], p[s+3]);
    ((float4*)(hend  + o))[s >> 2] = make_float4(h[s], h[s+1], h[s+2], h[s+3]);
  }
}

__global__ __launch_bounds__(64) void scan_comb_k(const float* __restrict__ prodA,
                                                  const float* __restrict__ hend,
                                                  float* __restrict__ hstart) {
  int idx = blockIdx.x * 64 + threadIdx.x;   // 0 .. SEQS-1
  float run = 0.f;
  #pragma unroll
  for (int c = 0; c < NCH; c++) {
    size_t o = (size_t)c * SEQS + idx;
    hstart[o] = run;
    run = prodA[o] * run + hend[o];
  }
}

__global__ __launch_bounds__(64) void scan_fin_k(const float* __restrict__ delta,
                                                 const float* __restrict__ xdbl,
                                                 const float* __restrict__ A_log,
                                                 const float* __restrict__ Dp,
                                                 const float* __restrict__ xc,
                                                 const float* __restrict__ z,
                                                 const float* __restrict__ hstart,
                                                 __hip_bfloat16* __restrict__ ypbf) {
  __shared__ float sBC[CHL * 32];
  const int t = threadIdx.x;
  const int dg = blockIdx.x % (DI / 64);
  const int chunk = (blockIdx.x / (DI / 64)) % NCH;
  const int b = blockIdx.x / ((DI / 64) * NCH);
  const int d = dg * 64 + t;

  float a[16];
  #pragma unroll
  for (int s = 0; s < 16; s++) a[s] = -__expf(A_log[s]);

  const float4* src = (const float4*)(xdbl + ((size_t)b * LL + chunk * CHL) * 32);
  #pragma unroll
  for (int k = 0; k < 8; k++) ((float4*)sBC)[t + k * 64] = src[t + k * 64];
  __syncthreads();

  float h[16];
  size_t o = (size_t)chunk * SEQS + ((size_t)b * DI + d) * 16;
  #pragma unroll
  for (int s = 0; s < 16; s += 4) {
    float4 v = ((const float4*)(hstart + o))[s >> 2];
    h[s] = v.x; h[s+1] = v.y; h[s+2] = v.z; h[s+3] = v.w;
  }
  const float Dv = Dp[d];

  const size_t rbase = (size_t)b * LL + chunk * CHL;
  const float* dptr = delta + rbase * DI + d;
  const float* xcp  = xc    + rbase * DI + d;
  const float* zp   = z     + rbase * DI + d;
  __hip_bfloat16* yp = ypbf + rbase * DI + d;

  #pragma unroll 2
  for (int i = 0; i < CHL; i++) {
    float dlt = dptr[(size_t)i * DI];
    const float4* bc = (const float4*)(sBC + i * 32);
    float4 B0 = bc[0], B1 = bc[1], B2 = bc[2], B3 = bc[3];
    float4 C0 = bc[4], C1 = bc[5], C2 = bc[6], C3 = bc[7];
    float Bv[16] = {B0.x,B0.y,B0.z,B0.w, B1.x,B1.y,B1.z,B1.w,
                    B2.x,B2.y,B2.z,B2.w, B3.x,B3.y,B3.z,B3.w};
    float Cv[16] = {C0.x,C0.y,C0.z,C0.w, C1.x,C1.y,C1.z,C1.w,
                    C2.x,C2.y,C2.z,C2.w, C3.x,C3.y,C3.z,C3.w};
    float y = 0.f;
    #pragma unroll
    for (int s = 0; s < 16; s++) {
      float dA = __expf(dlt * a[s]);
      h[s] = dA * h[s] + dlt * Bv[s];
      y += h[s] * Cv[s];
    }
    float xcv = xcp[(size_t)i * DI];
    float zv  = zp [(size_t)i * DI];
    float val = (y + Dv * xcv) * (zv / (1.f + __expf(-zv)));
    yp[(size_t)i * DI] = __float2bfloat16(val);
  }
}

extern "C" void kernel_launch(void* const* d_in, const int* in_sizes, int n_in,
                              void* d_out, int out_size, void* d_ws, size_t ws_size,
                              hipStream_t stream) {
  const float* x      = (const float*)d_in[0];
  const float* W_in   = (const float*)d_in[1];
  const float* W_conv = (const float*)d_in[2];
  const float* W_x    = (const float*)d_in[3];
  const float* W_dt   = (const float*)d_in[4];
  const float* b_dt   = (const float*)d_in[5];
  const float* A_log  = (const float*)d_in[6];
  const float* Dp     = (const float*)d_in[7];
  const float* W_out  = (const float*)d_in[8];
  float* out = (float*)d_out;

  char* ws = (char*)d_ws;
  // workspace layout (bytes), total 144441344
  float*          xpart  = (float*)(ws + 0);                         // 25165824
  float*          z      = (float*)(ws + 25165824);                  // 25165824
  __hip_bfloat16* xbf    = (__hip_bfloat16*)(ws + 50331648);         // 6291456 (dead after GEMM1)
  __hip_bfloat16* Winbf  = (__hip_bfloat16*)(ws + 56623104);         // 4718592
  float*          xc     = (float*)(ws + 61341696);                  // 25165824
  __hip_bfloat16* xcbf   = (__hip_bfloat16*)(ws + 86507520);         // 12582912
  float*          delta  = (float*)(ws + 103809024);                 // 25165824
  float*          xdbl   = (float*)(ws + 128974848);                 // 524288
  __hip_bfloat16* ypbf   = (__hip_bfloat16*)(ws + 129499136);        // 12582912
  __hip_bfloat16* Woutbf = (__hip_bfloat16*)(ws + 142082048);        // 2359296
  // aliases of dead regions:
  float*          prodA  = (float*)(ws + 0);                         // xpart region (dead after conv)
  float*          hend   = (float*)(ws + 6291456);
  float*          hstart = (float*)(ws + 12582912);
  __hip_bfloat16* Wcomb  = (__hip_bfloat16*)(ws + 50331648);         // xbf region: 1664*1536*2

  // fp32 -> bf16 converts
  cvt4_k<<<(786432 + 255) / 256, 256, 0, stream>>>(x, xbf, 786432);
  cvt4_k<<<(589824 + 255) / 256, 256, 0, stream>>>(W_in, Winbf, 589824);
  cvt4_k<<<(294912 + 255) / 256, 256, 0, stream>>>(W_out, Woutbf, 294912);

  // xz = x @ W_in.T (4096 x 3072, K=768), split-stored into xpart | z  [R5 kernel]
  {
    dim3 g(3072 / 128, 4096 / 128);   // 768 blocks
    gemm_db<2, 128><<<g, 256, 0, stream>>>(xbf, Winbf, xpart, z, nullptr, MM, 2 * DI, DM);
  }
  // xc = silu(causal_dwconv(xpart))
  conv_silu_k<<<(MM * DI + 255) / 256, 256, 0, stream>>>(xpart, W_conv, xc, xcbf);
  // Wcomb = [W_dt ; W_x ; 0] bf16 (aliases xbf, dead after GEMM1)
  wcomb_k<<<(NC2 * DI / 4 + 255) / 256, 256, 0, stream>>>(W_dt, W_x, Wcomb);
  // delta = softplus(xc @ W_dt.T + b_dt) AND xdbl = xc @ W_x.T  [NEW: LDS-free direct-frag]
  {
    dim3 g(NC2 / 128, 4096 / 128);    // 416 blocks
    gemm_df<3, DI><<<g, 256, 0, stream>>>(xcbf, Wcomb, delta, xdbl, b_dt, NC2);
  }
  // chunked selective scan + gating
  scan_part_k<<<BB * NCH * (DI / 64), 64, 0, stream>>>(delta, xdbl, A_log, prodA, hend);
  scan_comb_k<<<SEQS / 64, 64, 0, stream>>>(prodA, hend, hstart);
  scan_fin_k<<<BB * NCH * (DI / 64), 64, 0, stream>>>(delta, xdbl, A_log, Dp, xc, z,
                                                      hstart, ypbf);
  // out = y @ W_out.T (4096 x 768, K=1536)  [R5 kernel, BM=64 -> 384 blocks]
  {
    dim3 g(768 / 128, 4096 / 64);
    gemm_db<0, 64><<<g, 256, 0, stream>>>(ypbf, Woutbf, out, nullptr, nullptr, MM, DM, DI);
  }
}

// Round 10
// 345.866 us; speedup vs baseline: 1.2571x; 1.1455x over previous
//
#include <hip/hip_runtime.h>
#include <hip/hip_bf16.h>

// Problem constants (B=2, L=2048, Dm=768, di=1536, ds=16, dc=4)
#define BB 2
#define LL 2048
#define DM 768
#define DI 1536
#define DS 16
#define MM (BB*LL)   // 4096 rows
#define NCH 32       // scan chunks
#define CHL 64       // steps per chunk
#define SEQS (BB*DI*DS)  // 49152 independent scalar recurrences
#define NC2 1664     // delta GEMM fused N: 1536 (W_dt) + 32 (W_x) + 96 pad

typedef __hip_bfloat16 bf16;
typedef short bf16x8 __attribute__((ext_vector_type(8)));
typedef float f32x4  __attribute__((ext_vector_type(4)));

__device__ __forceinline__ void gl_lds16(const void* g, void* l) {
  __builtin_amdgcn_global_load_lds((const __attribute__((address_space(1))) void*)g,
                                   (__attribute__((address_space(3))) void*)l, 16, 0, 0);
}

// ---------------- merged prep: x/W_in/W_out -> bf16, build Wcomb ----------------
// Range-dispatched single kernel (replaces 3x cvt4_k + wcomb_k).
struct bf4 { __hip_bfloat16 a, b, c, d; };
#define PR0 786432                   // x: 4096*768/4
#define PR1 589824                   // W_in: 3072*768/4
#define PR2 294912                   // W_out: 768*1536/4
#define PR3 638976                   // Wcomb: 1664*1536/4
#define PRTOT (PR0+PR1+PR2+PR3)      // 2310144

__global__ __launch_bounds__(256) void prep_k(const float* __restrict__ x,
                                              const float* __restrict__ Win,
                                              const float* __restrict__ Wout,
                                              const float* __restrict__ Wdt,
                                              const float* __restrict__ Wx,
                                              __hip_bfloat16* __restrict__ xbf,
                                              __hip_bfloat16* __restrict__ Winbf,
                                              __hip_bfloat16* __restrict__ Woutbf,
                                              __hip_bfloat16* __restrict__ Wcomb) {
  int i = blockIdx.x * 256 + threadIdx.x;
  if (i >= PRTOT) return;
  float4 v; __hip_bfloat16* dst; int di_;
  if (i < PR0)                    { v = ((const float4*)x)[i];                 dst = xbf;    di_ = i; }
  else if (i < PR0 + PR1)         { di_ = i - PR0; v = ((const float4*)Win)[di_];  dst = Winbf; }
  else if (i < PR0 + PR1 + PR2)   { di_ = i - PR0 - PR1; v = ((const float4*)Wout)[di_]; dst = Woutbf; }
  else {
    di_ = i - PR0 - PR1 - PR2;    // Wcomb = [W_dt ; W_x ; 0-pad]
    int e = di_ * 4, row = e / DI, colb = e % DI;
    if (row < DI)            v = ((const float4*)Wdt)[di_];
    else if (row < DI + 32)  v = *(const float4*)(Wx + (size_t)(row - DI) * DI + colb);
    else                     v = make_float4(0.f, 0.f, 0.f, 0.f);
    dst = Wcomb;
  }
  bf4 o = { __float2bfloat16(v.x), __float2bfloat16(v.y),
            __float2bfloat16(v.z), __float2bfloat16(v.w) };
  ((bf4*)dst)[di_] = o;
}

// ---------------- R5 pipelined LDS-staged GEMM (proven config, bf16 epilogues) ----
// C[M,N] = A[M,K] * W[N,K]^T. 256 threads = 4 waves (2x2), wave tile (BM/2)x64.
// global_load_lds width=16, 3 LDS buffers, 2 tiles in flight, one
// vmcnt(NPW)+barrier per iter (loads stay in flight across it).
// EPI: 0 = plain fp32 store (stride N)                               [out GEMM]
//      5 = split bf16: col<DI -> C (stride DI), else -> C2 (stride DI) [xz GEMM]
//      6 = col<DI -> bf16(softplus(v+bias[col])) -> C (stride DI);
//          col in [DI,DI+32) -> fp32 C2 (stride 32); else discard   [delta+xdbl]
template<int EPI, int BM>
__global__ __launch_bounds__(256) void gemm_db(const bf16* __restrict__ A,
                                               const bf16* __restrict__ W,
                                               void* __restrict__ Cv,
                                               void* __restrict__ C2v,
                                               const float* __restrict__ bias,
                                               int M, int N, int K) {
  constexpr int NA  = BM / 64;
  constexpr int NPW = NA + 2;
  __shared__ short sA[3][BM * 32];
  __shared__ short sB[3][128 * 32];
  const int t = threadIdx.x;
  const int m0 = blockIdx.y * BM, n0 = blockIdx.x * 128;
  const int w = t >> 6, lane = t & 63;
  const int wm = (w >> 1) * (BM / 2), wn = (w & 1) * 64;
  const int ga = wm >> 4, gb = wn >> 4;

  f32x4 acc[BM / 32][4] = {};

  const int srow = lane & 15, skoff = (lane >> 4) * 8;
  const bf16* gA[NA]; const bf16* gB[2];
  #pragma unroll
  for (int j = 0; j < NA; j++)
    gA[j] = A + (size_t)(m0 + (w + 4 * j) * 16 + srow) * K + skoff;
  #pragma unroll
  for (int j = 0; j < 2; j++)
    gB[j] = W + (size_t)(n0 + (w + 4 * j) * 16 + srow) * K + skoff;

  #define ISSUE(buf, k0)                                              \
    do {                                                              \
      _Pragma("unroll")                                               \
      for (int j = 0; j < NA; j++)                                    \
        gl_lds16(gA[j] + (k0), &sA[buf][(w + 4 * j) * 512]);          \
      _Pragma("unroll")                                               \
      for (int j = 0; j < 2; j++)                                     \
        gl_lds16(gB[j] + (k0), &sB[buf][(w + 4 * j) * 512]);          \
    } while (0)

  ISSUE(0, 0);
  ISSUE(1, 32);
  int p = 0;
  for (int k0 = 0; k0 < K; k0 += 32) {
    if (k0 + 32 < K) {
      asm volatile("s_waitcnt vmcnt(%0)\n\ts_barrier" :: "n"(NPW) : "memory");
    } else {
      asm volatile("s_waitcnt vmcnt(0)\n\ts_barrier" ::: "memory");
    }
    if (k0 + 64 < K) {
      int nb = p + 2; if (nb >= 3) nb -= 3;
      ISSUE(nb, k0 + 64);
    }
    const bf16x8* fA = (const bf16x8*)sA[p];
    const bf16x8* fB = (const bf16x8*)sB[p];
    bf16x8 af[BM / 32], bfr[4];
    #pragma unroll
    for (int i = 0; i < BM / 32; i++) af[i]  = fA[(ga + i) * 64 + lane];
    #pragma unroll
    for (int j = 0; j < 4; j++)       bfr[j] = fB[(gb + j) * 64 + lane];
    #pragma unroll
    for (int i = 0; i < BM / 32; i++)
      #pragma unroll
      for (int j = 0; j < 4; j++)
        acc[i][j] = __builtin_amdgcn_mfma_f32_16x16x32_bf16(af[i], bfr[j], acc[i][j], 0, 0, 0);
    p++; if (p >= 3) p = 0;
  }
  #undef ISSUE

  const int q = lane >> 4, mm = lane & 15;
  #pragma unroll
  for (int i = 0; i < BM / 32; i++)
    #pragma unroll
    for (int j = 0; j < 4; j++) {
      int r0  = m0 + wm + i * 16 + q * 4;
      int col = n0 + wn + j * 16 + mm;
      #pragma unroll
      for (int r = 0; r < 4; r++) {
        float v = acc[i][j][r];
        if (EPI == 0) {
          ((float*)Cv)[(size_t)(r0 + r) * N + col] = v;
        } else if (EPI == 5) {
          if (col < DI) ((bf16*)Cv) [(size_t)(r0 + r) * DI + col]        = __float2bfloat16(v);
          else          ((bf16*)C2v)[(size_t)(r0 + r) * DI + (col - DI)] = __float2bfloat16(v);
        } else {  // EPI == 6
          if (col < DI) {
            float vv = v + bias[col];
            vv = (vv > 15.f) ? vv : __logf(1.f + __expf(vv));
            ((bf16*)Cv)[(size_t)(r0 + r) * DI + col] = __float2bfloat16(vv);
          } else if (col < DI + 32) {
            ((float*)C2v)[(size_t)(r0 + r) * 32 + (col - DI)] = v;
          }
        }
      }
    }
}

// ---------------- depthwise causal conv (dc=4) + SiLU; bf16 in/out ----------------
__global__ __launch_bounds__(256) void conv_silu_k(const bf16* __restrict__ xpart,
                                                   const float* __restrict__ Wc,
                                                   __hip_bfloat16* __restrict__ xcbf) {
  int idx = blockIdx.x * 256 + threadIdx.x;
  if (idx >= MM * DI) return;
  int d = idx % DI;
  int r = idx / DI;
  int l = r & (LL - 1);
  float4 wv = ((const float4*)Wc)[d];  // W_conv[d, 0, 0..3]
  const bf16* xp = xpart + (size_t)r * DI + d;
  float acc = wv.w * __bfloat162float(xp[0]);
  if (l >= 1) acc += wv.z * __bfloat162float(xp[-(ptrdiff_t)DI]);
  if (l >= 2) acc += wv.y * __bfloat162float(xp[-(ptrdiff_t)(2 * DI)]);
  if (l >= 3) acc += wv.x * __bfloat162float(xp[-(ptrdiff_t)(3 * DI)]);
  float s = acc / (1.f + __expf(-acc));   // silu
  xcbf[idx] = __float2bfloat16(s);
}

// ================= chunked selective scan (delta/xc/z in bf16) =================
__global__ __launch_bounds__(64) void scan_part_k(const bf16* __restrict__ delta,
                                                  const float* __restrict__ xdbl,
                                                  const float* __restrict__ A_log,
                                                  float* __restrict__ prodA,
                                                  float* __restrict__ hend) {
  __shared__ float sBC[CHL * 32];
  const int t = threadIdx.x;
  const int dg = blockIdx.x % (DI / 64);
  const int chunk = (blockIdx.x / (DI / 64)) % NCH;
  const int b = blockIdx.x / ((DI / 64) * NCH);
  const int d = dg * 64 + t;

  float a[16];
  #pragma unroll
  for (int s = 0; s < 16; s++) a[s] = -__expf(A_log[s]);

  const float4* src = (const float4*)(xdbl + ((size_t)b * LL + chunk * CHL) * 32);
  #pragma unroll
  for (int k = 0; k < 8; k++) ((float4*)sBC)[t + k * 64] = src[t + k * 64];
  __syncthreads();

  float h[16], p[16];
  #pragma unroll
  for (int s = 0; s < 16; s++) { h[s] = 0.f; p[s] = 1.f; }

  const bf16* dptr = delta + ((size_t)b * LL + chunk * CHL) * DI + d;
  #pragma unroll 2
  for (int i = 0; i < CHL; i++) {
    float dlt = __bfloat162float(dptr[(size_t)i * DI]);
    const float4* bc = (const float4*)(sBC + i * 32);
    float4 B0 = bc[0], B1 = bc[1], B2 = bc[2], B3 = bc[3];
    float Bv[16] = {B0.x,B0.y,B0.z,B0.w, B1.x,B1.y,B1.z,B1.w,
                    B2.x,B2.y,B2.z,B2.w, B3.x,B3.y,B3.z,B3.w};
    #pragma unroll
    for (int s = 0; s < 16; s++) {
      float dA = __expf(dlt * a[s]);
      h[s] = dA * h[s] + dlt * Bv[s];
      p[s] *= dA;
    }
  }
  size_t o = (size_t)chunk * SEQS + ((size_t)b * DI + d) * 16;
  #pragma unroll
  for (int s = 0; s < 16; s += 4) {
    ((float4*)(prodA + o))[s >> 2] = make_float4(p[s], p[s+1], p[s+2], p[s+3]);
    ((float4*)(hend  + o))[s >> 2] = make_float4(h[s], h[s+1], h[s+2], h[s+3]);
  }
}

__global__ __launch_bounds__(64) void scan_comb_k(const float* __restrict__ prodA,
                                                  const float* __restrict__ hend,
                                                  float* __restrict__ hstart) {
  int idx = blockIdx.x * 64 + threadIdx.x;   // 0 .. SEQS-1
  float run = 0.f;
  #pragma unroll
  for (int c = 0; c < NCH; c++) {
    size_t o = (size_t)c * SEQS + idx;
    hstart[o] = run;
    run = prodA[o] * run + hend[o];
  }
}

__global__ __launch_bounds__(64) void scan_fin_k(const bf16* __restrict__ delta,
                                                 const float* __restrict__ xdbl,
                                                 const float* __restrict__ A_log,
                                                 const float* __restrict__ Dp,
                                                 const bf16* __restrict__ xcbf,
                                                 const bf16* __restrict__ zbf,
                                                 const float* __restrict__ hstart,
                                                 __hip_bfloat16* __restrict__ ypbf) {
  __shared__ float sBC[CHL * 32];
  const int t = threadIdx.x;
  const int dg = blockIdx.x % (DI / 64);
  const int chunk = (blockIdx.x / (DI / 64)) % NCH;
  const int b = blockIdx.x / ((DI / 64) * NCH);
  const int d = dg * 64 + t;

  float a[16];
  #pragma unroll
  for (int s = 0; s < 16; s++) a[s] = -__expf(A_log[s]);

  const float4* src = (const float4*)(xdbl + ((size_t)b * LL + chunk * CHL) * 32);
  #pragma unroll
  for (int k = 0; k < 8; k++) ((float4*)sBC)[t + k * 64] = src[t + k * 64];
  __syncthreads();

  float h[16];
  size_t o = (size_t)chunk * SEQS + ((size_t)b * DI + d) * 16;
  #pragma unroll
  for (int s = 0; s < 16; s += 4) {
    float4 v = ((const float4*)(hstart + o))[s >> 2];
    h[s] = v.x; h[s+1] = v.y; h[s+2] = v.z; h[s+3] = v.w;
  }
  const float Dv = Dp[d];

  const size_t rbase = (size_t)b * LL + chunk * CHL;
  const bf16* dptr = delta + rbase * DI + d;
  const bf16* xcp  = xcbf  + rbase * DI + d;
  const bf16* zp   = zbf   + rbase * DI + d;
  __hip_bfloat16* yp = ypbf + rbase * DI + d;

  #pragma unroll 2
  for (int i = 0; i < CHL; i++) {
    float dlt = __bfloat162float(dptr[(size_t)i * DI]);
    const float4* bc = (const float4*)(sBC + i * 32);
    float4 B0 = bc[0], B1 = bc[1], B2 = bc[2], B3 = bc[3];
    float4 C0 = bc[4], C1 = bc[5], C2 = bc[6], C3 = bc[7];
    float Bv[16] = {B0.x,B0.y,B0.z,B0.w, B1.x,B1.y,B1.z,B1.w,
                    B2.x,B2.y,B2.z,B2.w, B3.x,B3.y,B3.z,B3.w};
    float Cv[16] = {C0.x,C0.y,C0.z,C0.w, C1.x,C1.y,C1.z,C1.w,
                    C2.x,C2.y,C2.z,C2.w, C3.x,C3.y,C3.z,C3.w};
    float y = 0.f;
    #pragma unroll
    for (int s = 0; s < 16; s++) {
      float dA = __expf(dlt * a[s]);
      h[s] = dA * h[s] + dlt * Bv[s];
      y += h[s] * Cv[s];
    }
    float xcv = __bfloat162float(xcp[(size_t)i * DI]);
    float zv  = __bfloat162float(zp [(size_t)i * DI]);
    float val = (y + Dv * xcv) * (zv / (1.f + __expf(-zv)));
    yp[(size_t)i * DI] = __float2bfloat16(val);
  }
}

extern "C" void kernel_launch(void* const* d_in, const int* in_sizes, int n_in,
                              void* d_out, int out_size, void* d_ws, size_t ws_size,
                              hipStream_t stream) {
  const float* x      = (const float*)d_in[0];
  const float* W_in   = (const float*)d_in[1];
  const float* W_conv = (const float*)d_in[2];
  const float* W_x    = (const float*)d_in[3];
  const float* W_dt   = (const float*)d_in[4];
  const float* b_dt   = (const float*)d_in[5];
  const float* A_log  = (const float*)d_in[6];
  const float* Dp     = (const float*)d_in[7];
  const float* W_out  = (const float*)d_in[8];
  float* out = (float*)d_out;

  char* ws = (char*)d_ws;
  // workspace layout (bytes), total 100794368 (< previous 144441344 budget)
  bf16*  xpartbf = (bf16*)(ws + 0);          // 4096*1536*2 = 12582912
  bf16*  zbf     = (bf16*)(ws + 12582912);   // 12582912
  bf16*  xbf     = (bf16*)(ws + 25165824);   // 4096*768*2  =  6291456
  bf16*  Winbf   = (bf16*)(ws + 31457280);   // 3072*768*2  =  4718592
  bf16*  xcbf    = (bf16*)(ws + 36175872);   // 12582912
  bf16*  Wcomb   = (bf16*)(ws + 48758784);   // 1664*1536*2 =  5111808
  bf16*  deltabf = (bf16*)(ws + 53870592);   // 12582912
  float* xdbl    = (float*)(ws + 66453504);  // 4096*32*4   =   524288
  bf16*  ypbf    = (bf16*)(ws + 66977792);   // 12582912
  bf16*  Woutbf  = (bf16*)(ws + 79560704);   // 768*1536*2  =  2359296
  float* prodA   = (float*)(ws + 81920000);  // 32*49152*4  =  6291456
  float* hend    = (float*)(ws + 88211456);  // 6291456
  float* hstart  = (float*)(ws + 94502912);  // 6291456

  // merged prep: bf16 converts + Wcomb build (1 launch, was 4)
  prep_k<<<(PRTOT + 255) / 256, 256, 0, stream>>>(x, W_in, W_out, W_dt, W_x,
                                                  xbf, Winbf, Woutbf, Wcomb);

  // xz = x @ W_in.T (4096 x 3072, K=768), split bf16 stores into xpartbf | zbf
  {
    dim3 g(3072 / 128, 4096 / 128);   // 768 blocks
    gemm_db<5, 128><<<g, 256, 0, stream>>>(xbf, Winbf, xpartbf, zbf, nullptr, MM, 2 * DI, DM);
  }
  // xc = silu(causal_dwconv(xpart)), bf16 only
  conv_silu_k<<<(MM * DI + 255) / 256, 256, 0, stream>>>(xpartbf, W_conv, xcbf);
  // delta = bf16(softplus(xc @ W_dt.T + b_dt)) AND xdbl = xc @ W_x.T (fp32), one GEMM
  {
    dim3 g(NC2 / 128, 4096 / 128);    // 416 blocks
    gemm_db<6, 128><<<g, 256, 0, stream>>>(xcbf, Wcomb, deltabf, xdbl, b_dt, MM, NC2, DI);
  }
  // chunked selective scan + gating
  scan_part_k<<<BB * NCH * (DI / 64), 64, 0, stream>>>(deltabf, xdbl, A_log, prodA, hend);
  scan_comb_k<<<SEQS / 64, 64, 0, stream>>>(prodA, hend, hstart);
  scan_fin_k<<<BB * NCH * (DI / 64), 64, 0, stream>>>(deltabf, xdbl, A_log, Dp, xcbf, zbf,
                                                      hstart, ypbf);
  // out = y @ W_out.T (4096 x 768, K=1536), fp32 out  [R5 config, BM=64 -> 384 blocks]
  {
    dim3 g(768 / 128, 4096 / 64);
    gemm_db<0, 64><<<g, 256, 0, stream>>>(ypbf, Woutbf, out, nullptr, nullptr, MM, DM, DI);
  }
}

// Round 11
// 336.245 us; speedup vs baseline: 1.2930x; 1.0286x over previous
//
#include <hip/hip_runtime.h>
#include <hip/hip_bf16.h>

// Problem constants (B=2, L=2048, Dm=768, di=1536, ds=16, dc=4)
#define BB 2
#define LL 2048
#define DM 768
#define DI 1536
#define DS 16
#define MM (BB*LL)   // 4096 rows
#define NCH 64       // scan chunks (was 32; more TLP)
#define CHL 32       // steps per chunk
#define SEQS (BB*DI*DS)  // 49152 independent scalar recurrences
#define NC2 1664     // delta GEMM fused N: 1536 (W_dt) + 32 (W_x) + 96 pad

typedef __hip_bfloat16 bf16;
typedef short bf16x8 __attribute__((ext_vector_type(8)));
typedef float f32x4  __attribute__((ext_vector_type(4)));

__device__ __forceinline__ void gl_lds16(const void* g, void* l) {
  __builtin_amdgcn_global_load_lds((const __attribute__((address_space(1))) void*)g,
                                   (__attribute__((address_space(3))) void*)l, 16, 0, 0);
}

// ---------------- merged prep: x/W_in/W_out -> bf16, build Wcomb ----------------
struct bf4 { __hip_bfloat16 a, b, c, d; };
#define PR0 786432                   // x: 4096*768/4
#define PR1 589824                   // W_in: 3072*768/4
#define PR2 294912                   // W_out: 768*1536/4
#define PR3 638976                   // Wcomb: 1664*1536/4
#define PRTOT (PR0+PR1+PR2+PR3)      // 2310144

__global__ __launch_bounds__(256) void prep_k(const float* __restrict__ x,
                                              const float* __restrict__ Win,
                                              const float* __restrict__ Wout,
                                              const float* __restrict__ Wdt,
                                              const float* __restrict__ Wx,
                                              __hip_bfloat16* __restrict__ xbf,
                                              __hip_bfloat16* __restrict__ Winbf,
                                              __hip_bfloat16* __restrict__ Woutbf,
                                              __hip_bfloat16* __restrict__ Wcomb) {
  int i = blockIdx.x * 256 + threadIdx.x;
  if (i >= PRTOT) return;
  float4 v; __hip_bfloat16* dst; int di_;
  if (i < PR0)                    { v = ((const float4*)x)[i];                 dst = xbf;    di_ = i; }
  else if (i < PR0 + PR1)         { di_ = i - PR0; v = ((const float4*)Win)[di_];  dst = Winbf; }
  else if (i < PR0 + PR1 + PR2)   { di_ = i - PR0 - PR1; v = ((const float4*)Wout)[di_]; dst = Woutbf; }
  else {
    di_ = i - PR0 - PR1 - PR2;    // Wcomb = [W_dt ; W_x ; 0-pad]
    int e = di_ * 4, row = e / DI, colb = e % DI;
    if (row < DI)            v = ((const float4*)Wdt)[di_];
    else if (row < DI + 32)  v = *(const float4*)(Wx + (size_t)(row - DI) * DI + colb);
    else                     v = make_float4(0.f, 0.f, 0.f, 0.f);
    dst = Wcomb;
  }
  bf4 o = { __float2bfloat16(v.x), __float2bfloat16(v.y),
            __float2bfloat16(v.z), __float2bfloat16(v.w) };
  ((bf4*)dst)[di_] = o;
}

// ---------------- R5 pipelined LDS-staged GEMM (proven config) ----------------
// C[M,N] = A[M,K_sub] * W[N,K_sub]^T where K_sub = K cols starting at
// blockIdx.z*K within row stride Kstride (split-K via separate partials, no RMW).
// 256 threads = 4 waves (2x2), wave tile 64x64 (16 MFMA/iter), 3 LDS buffers,
// 2 tiles in flight, one vmcnt(NPW)+barrier per iter.
// EPI: 0 = plain fp32 store (stride N)                               [out GEMM]
//      5 = split bf16: col<DI -> C (stride DI), else -> C2 (stride DI) [xz GEMM]
//      6 = col<DI -> bf16(softplus(v+bias[col])) -> C (stride DI);
//          col in [DI,DI+32) -> fp32 C2 (stride 32); else discard   [delta+xdbl]
//      7 = fp32 partial store at C + blockIdx.z*M*N                 [split-K out]
template<int EPI, int BM>
__global__ __launch_bounds__(256) void gemm_db(const bf16* __restrict__ A,
                                               const bf16* __restrict__ W,
                                               void* __restrict__ Cv,
                                               void* __restrict__ C2v,
                                               const float* __restrict__ bias,
                                               int M, int N, int K, int Kstride) {
  constexpr int NA  = BM / 64;
  constexpr int NPW = NA + 2;
  __shared__ short sA[3][BM * 32];
  __shared__ short sB[3][128 * 32];
  const int t = threadIdx.x;
  const int m0 = blockIdx.y * BM, n0 = blockIdx.x * 128;
  const size_t koff = (size_t)blockIdx.z * K;
  const int w = t >> 6, lane = t & 63;
  const int wm = (w >> 1) * (BM / 2), wn = (w & 1) * 64;
  const int ga = wm >> 4, gb = wn >> 4;

  f32x4 acc[BM / 32][4] = {};

  const int srow = lane & 15, skoff = (lane >> 4) * 8;
  const bf16* gA[NA]; const bf16* gB[2];
  #pragma unroll
  for (int j = 0; j < NA; j++)
    gA[j] = A + (size_t)(m0 + (w + 4 * j) * 16 + srow) * Kstride + koff + skoff;
  #pragma unroll
  for (int j = 0; j < 2; j++)
    gB[j] = W + (size_t)(n0 + (w + 4 * j) * 16 + srow) * Kstride + koff + skoff;

  #define ISSUE(buf, k0)                                              \
    do {                                                              \
      _Pragma("unroll")                                               \
      for (int j = 0; j < NA; j++)                                    \
        gl_lds16(gA[j] + (k0), &sA[buf][(w + 4 * j) * 512]);          \
      _Pragma("unroll")                                               \
      for (int j = 0; j < 2; j++)                                     \
        gl_lds16(gB[j] + (k0), &sB[buf][(w + 4 * j) * 512]);          \
    } while (0)

  ISSUE(0, 0);
  ISSUE(1, 32);
  int p = 0;
  for (int k0 = 0; k0 < K; k0 += 32) {
    if (k0 + 32 < K) {
      asm volatile("s_waitcnt vmcnt(%0)\n\ts_barrier" :: "n"(NPW) : "memory");
    } else {
      asm volatile("s_waitcnt vmcnt(0)\n\ts_barrier" ::: "memory");
    }
    if (k0 + 64 < K) {
      int nb = p + 2; if (nb >= 3) nb -= 3;
      ISSUE(nb, k0 + 64);
    }
    const bf16x8* fA = (const bf16x8*)sA[p];
    const bf16x8* fB = (const bf16x8*)sB[p];
    bf16x8 af[BM / 32], bfr[4];
    #pragma unroll
    for (int i = 0; i < BM / 32; i++) af[i]  = fA[(ga + i) * 64 + lane];
    #pragma unroll
    for (int j = 0; j < 4; j++)       bfr[j] = fB[(gb + j) * 64 + lane];
    #pragma unroll
    for (int i = 0; i < BM / 32; i++)
      #pragma unroll
      for (int j = 0; j < 4; j++)
        acc[i][j] = __builtin_amdgcn_mfma_f32_16x16x32_bf16(af[i], bfr[j], acc[i][j], 0, 0, 0);
    p++; if (p >= 3) p = 0;
  }
  #undef ISSUE

  const int q = lane >> 4, mm = lane & 15;
  #pragma unroll
  for (int i = 0; i < BM / 32; i++)
    #pragma unroll
    for (int j = 0; j < 4; j++) {
      int r0  = m0 + wm + i * 16 + q * 4;
      int col = n0 + wn + j * 16 + mm;
      #pragma unroll
      for (int r = 0; r < 4; r++) {
        float v = acc[i][j][r];
        if (EPI == 0) {
          ((float*)Cv)[(size_t)(r0 + r) * N + col] = v;
        } else if (EPI == 5) {
          if (col < DI) ((bf16*)Cv) [(size_t)(r0 + r) * DI + col]        = __float2bfloat16(v);
          else          ((bf16*)C2v)[(size_t)(r0 + r) * DI + (col - DI)] = __float2bfloat16(v);
        } else if (EPI == 6) {
          if (col < DI) {
            float vv = v + bias[col];
            vv = (vv > 15.f) ? vv : __logf(1.f + __expf(vv));
            ((bf16*)Cv)[(size_t)(r0 + r) * DI + col] = __float2bfloat16(vv);
          } else if (col < DI + 32) {
            ((float*)C2v)[(size_t)(r0 + r) * 32 + (col - DI)] = v;
          }
        } else {  // EPI == 7: split-K partial
          ((float*)Cv)[(size_t)blockIdx.z * M * N + (size_t)(r0 + r) * N + col] = v;
        }
      }
    }
}

// ---------------- split-K reduce: out = P0 + P1 (fp32, float4) ----------------
__global__ __launch_bounds__(256) void redk_k(const float4* __restrict__ P,
                                              float4* __restrict__ out, int n4) {
  int i = blockIdx.x * 256 + threadIdx.x;
  if (i >= n4) return;
  float4 a = P[i], b = P[i + n4];
  out[i] = make_float4(a.x + b.x, a.y + b.y, a.z + b.z, a.w + b.w);
}

// ---------------- depthwise causal conv (dc=4) + SiLU; bf16 in/out ----------------
__global__ __launch_bounds__(256) void conv_silu_k(const bf16* __restrict__ xpart,
                                                   const float* __restrict__ Wc,
                                                   __hip_bfloat16* __restrict__ xcbf) {
  int idx = blockIdx.x * 256 + threadIdx.x;
  if (idx >= MM * DI) return;
  int d = idx % DI;
  int r = idx / DI;
  int l = r & (LL - 1);
  float4 wv = ((const float4*)Wc)[d];  // W_conv[d, 0, 0..3]
  const bf16* xp = xpart + (size_t)r * DI + d;
  float acc = wv.w * __bfloat162float(xp[0]);
  if (l >= 1) acc += wv.z * __bfloat162float(xp[-(ptrdiff_t)DI]);
  if (l >= 2) acc += wv.y * __bfloat162float(xp[-(ptrdiff_t)(2 * DI)]);
  if (l >= 3) acc += wv.x * __bfloat162float(xp[-(ptrdiff_t)(3 * DI)]);
  float s = acc / (1.f + __expf(-acc));   // silu
  xcbf[idx] = __float2bfloat16(s);
}

// ================= chunked selective scan (NCH=64, CHL=32) =================
__global__ __launch_bounds__(64) void scan_part_k(const bf16* __restrict__ delta,
                                                  const float* __restrict__ xdbl,
                                                  const float* __restrict__ A_log,
                                                  float* __restrict__ prodA,
                                                  float* __restrict__ hend) {
  __shared__ float sBC[CHL * 32];
  const int t = threadIdx.x;
  const int dg = blockIdx.x % (DI / 64);
  const int chunk = (blockIdx.x / (DI / 64)) % NCH;
  const int b = blockIdx.x / ((DI / 64) * NCH);
  const int d = dg * 64 + t;

  float a[16];
  #pragma unroll
  for (int s = 0; s < 16; s++) a[s] = -__expf(A_log[s]);

  const float4* src = (const float4*)(xdbl + ((size_t)b * LL + chunk * CHL) * 32);
  #pragma unroll
  for (int k = 0; k < CHL * 32 / 4 / 64; k++) ((float4*)sBC)[t + k * 64] = src[t + k * 64];
  __syncthreads();

  float h[16], p[16];
  #pragma unroll
  for (int s = 0; s < 16; s++) { h[s] = 0.f; p[s] = 1.f; }

  const bf16* dptr = delta + ((size_t)b * LL + chunk * CHL) * DI + d;
  #pragma unroll 2
  for (int i = 0; i < CHL; i++) {
    float dlt = __bfloat162float(dptr[(size_t)i * DI]);
    const float4* bc = (const float4*)(sBC + i * 32);
    float4 B0 = bc[0], B1 = bc[1], B2 = bc[2], B3 = bc[3];
    float Bv[16] = {B0.x,B0.y,B0.z,B0.w, B1.x,B1.y,B1.z,B1.w,
                    B2.x,B2.y,B2.z,B2.w, B3.x,B3.y,B3.z,B3.w};
    #pragma unroll
    for (int s = 0; s < 16; s++) {
      float dA = __expf(dlt * a[s]);
      h[s] = dA * h[s] + dlt * Bv[s];
      p[s] *= dA;
    }
  }
  size_t o = (size_t)chunk * SEQS + ((size_t)b * DI + d) * 16;
  #pragma unroll
  for (int s = 0; s < 16; s += 4) {
    ((float4*)(prodA + o))[s >> 2] = make_float4(p[s], p[s+1], p[s+2], p[s+3]);
    ((float4*)(hend  + o))[s >> 2] = make_float4(h[s], h[s+1], h[s+2], h[s+3]);
  }
}

__global__ __launch_bounds__(64) void scan_comb_k(const float* __restrict__ prodA,
                                                  const float* __restrict__ hend,
                                                  float* __restrict__ hstart) {
  int idx = blockIdx.x * 64 + threadIdx.x;   // 0 .. SEQS-1
  float run = 0.f;
  #pragma unroll 4
  for (int c = 0; c < NCH; c++) {
    size_t o = (size_t)c * SEQS + idx;
    hstart[o] = run;
    run = prodA[o] * run + hend[o];
  }
}

__global__ __launch_bounds__(64) void scan_fin_k(const bf16* __restrict__ delta,
                                                 const float* __restrict__ xdbl,
                                                 const float* __restrict__ A_log,
                                                 const float* __restrict__ Dp,
                                                 const bf16* __restrict__ xcbf,
                                                 const bf16* __restrict__ zbf,
                                                 const float* __restrict__ hstart,
                                                 __hip_bfloat16* __restrict__ ypbf) {
  __shared__ float sBC[CHL * 32];
  const int t = threadIdx.x;
  const int dg = blockIdx.x % (DI / 64);
  const int chunk = (blockIdx.x / (DI / 64)) % NCH;
  const int b = blockIdx.x / ((DI / 64) * NCH);
  const int d = dg * 64 + t;

  float a[16];
  #pragma unroll
  for (int s = 0; s < 16; s++) a[s] = -__expf(A_log[s]);

  const float4* src = (const float4*)(xdbl + ((size_t)b * LL + chunk * CHL) * 32);
  #pragma unroll
  for (int k = 0; k < CHL * 32 / 4 / 64; k++) ((float4*)sBC)[t + k * 64] = src[t + k * 64];
  __syncthreads();

  float h[16];
  size_t o = (size_t)chunk * SEQS + ((size_t)b * DI + d) * 16;
  #pragma unroll
  for (int s = 0; s < 16; s += 4) {
    float4 v = ((const float4*)(hstart + o))[s >> 2];
    h[s] = v.x; h[s+1] = v.y; h[s+2] = v.z; h[s+3] = v.w;
  }
  const float Dv = Dp[d];

  const size_t rbase = (size_t)b * LL + chunk * CHL;
  const bf16* dptr = delta + rbase * DI + d;
  const bf16* xcp  = xcbf  + rbase * DI + d;
  const bf16* zp   = zbf   + rbase * DI + d;
  __hip_bfloat16* yp = ypbf + rbase * DI + d;

  #pragma unroll 2
  for (int i = 0; i < CHL; i++) {
    float dlt = __bfloat162float(dptr[(size_t)i * DI]);
    const float4* bc = (const float4*)(sBC + i * 32);
    float4 B0 = bc[0], B1 = bc[1], B2 = bc[2], B3 = bc[3];
    float4 C0 = bc[4], C1 = bc[5], C2 = bc[6], C3 = bc[7];
    float Bv[16] = {B0.x,B0.y,B0.z,B0.w, B1.x,B1.y,B1.z,B1.w,
                    B2.x,B2.y,B2.z,B2.w, B3.x,B3.y,B3.z,B3.w};
    float Cv[16] = {C0.x,C0.y,C0.z,C0.w, C1.x,C1.y,C1.z,C1.w,
                    C2.x,C2.y,C2.z,C2.w, C3.x,C3.y,C3.z,C3.w};
    float y = 0.f;
    #pragma unroll
    for (int s = 0; s < 16; s++) {
      float dA = __expf(dlt * a[s]);
      h[s] = dA * h[s] + dlt * Bv[s];
      y += h[s] * Cv[s];
    }
    float xcv = __bfloat162float(xcp[(size_t)i * DI]);
    float zv  = __bfloat162float(zp [(size_t)i * DI]);
    float val = (y + Dv * xcv) * (zv / (1.f + __expf(-zv)));
    yp[(size_t)i * DI] = __float2bfloat16(val);
  }
}

extern "C" void kernel_launch(void* const* d_in, const int* in_sizes, int n_in,
                              void* d_out, int out_size, void* d_ws, size_t ws_size,
                              hipStream_t stream) {
  const float* x      = (const float*)d_in[0];
  const float* W_in   = (const float*)d_in[1];
  const float* W_conv = (const float*)d_in[2];
  const float* W_x    = (const float*)d_in[3];
  const float* W_dt   = (const float*)d_in[4];
  const float* b_dt   = (const float*)d_in[5];
  const float* A_log  = (const float*)d_in[6];
  const float* Dp     = (const float*)d_in[7];
  const float* W_out  = (const float*)d_in[8];
  float* out = (float*)d_out;

  char* ws = (char*)d_ws;
  // workspace layout (bytes), max used = 119668736
  bf16*  xpartbf = (bf16*)(ws + 0);          // 12582912 (dead after conv)
  bf16*  zbf     = (bf16*)(ws + 12582912);   // 12582912 (dead after scan_fin)
  bf16*  xbf     = (bf16*)(ws + 25165824);   //  6291456 (dead after GEMM1)
  bf16*  Winbf   = (bf16*)(ws + 31457280);   //  4718592 (dead after GEMM1)
  bf16*  xcbf    = (bf16*)(ws + 36175872);   // 12582912
  bf16*  Wcomb   = (bf16*)(ws + 48758784);   //  5111808
  bf16*  deltabf = (bf16*)(ws + 53870592);   // 12582912
  float* xdbl    = (float*)(ws + 66453504);  //   524288
  bf16*  ypbf    = (bf16*)(ws + 66977792);   // 12582912
  bf16*  Woutbf  = (bf16*)(ws + 79560704);   //  2359296
  float* prodA   = (float*)(ws + 81920000);  // 64*49152*4 = 12582912
  float* hend    = (float*)(ws + 94502912);  // 12582912
  float* hstart  = (float*)(ws + 107085824); // 12582912
  // GEMM3 split-K partials alias [0, 25165824) (xpartbf+zbf, both dead by then):
  float* P3      = (float*)(ws + 0);         // 2 * 4096*768*4 = 25165824

  // merged prep: bf16 converts + Wcomb build
  prep_k<<<(PRTOT + 255) / 256, 256, 0, stream>>>(x, W_in, W_out, W_dt, W_x,
                                                  xbf, Winbf, Woutbf, Wcomb);

  // xz = x @ W_in.T (4096 x 3072, K=768), split bf16 stores into xpartbf | zbf
  {
    dim3 g(3072 / 128, 4096 / 128, 1);   // 768 blocks
    gemm_db<5, 128><<<g, 256, 0, stream>>>(xbf, Winbf, xpartbf, zbf, nullptr,
                                           MM, 2 * DI, DM, DM);
  }
  // xc = silu(causal_dwconv(xpart)), bf16
  conv_silu_k<<<(MM * DI + 255) / 256, 256, 0, stream>>>(xpartbf, W_conv, xcbf);
  // delta = bf16(softplus(xc @ W_dt.T + b_dt)) AND xdbl = xc @ W_x.T (fp32)
  {
    dim3 g(NC2 / 128, 4096 / 128, 1);    // 416 blocks
    gemm_db<6, 128><<<g, 256, 0, stream>>>(xcbf, Wcomb, deltabf, xdbl, b_dt,
                                           MM, NC2, DI, DI);
  }
  // chunked selective scan + gating (NCH=64 -> 3072 blocks, 12 waves/CU)
  scan_part_k<<<BB * NCH * (DI / 64), 64, 0, stream>>>(deltabf, xdbl, A_log, prodA, hend);
  scan_comb_k<<<SEQS / 64, 64, 0, stream>>>(prodA, hend, hstart);
  scan_fin_k<<<BB * NCH * (DI / 64), 64, 0, stream>>>(deltabf, xdbl, A_log, Dp, xcbf, zbf,
                                                      hstart, ypbf);
  // out = y @ W_out.T (4096 x 768, K=1536): split-K=2, density-16 tiles,
  // 384 blocks x 24 iters (vs R10's 384 x 48 at density-8), partials + reduce
  {
    dim3 g(768 / 128, 4096 / 128, 2);
    gemm_db<7, 128><<<g, 256, 0, stream>>>(ypbf, Woutbf, P3, nullptr, nullptr,
                                           MM, DM, DI / 2, DI);
  }
  redk_k<<<(786432 + 255) / 256, 256, 0, stream>>>((const float4*)P3, (float4*)out, 786432);
}